// Round 1
// baseline (316.609 us; speedup 1.0000x reference)
//
#include <hip/hip_runtime.h>
#include <math.h>

#define BB 4
#define HH 4
#define NSRC 2048
#define NDST 2048
#define IND 256
#define OUTD 64
#define ALPHA 0.2f

// workspace layout (float offsets)
#define SZ_HDST  (BB*HH*NDST*OUTD)            // 2097152
#define SZ_A     (BB*HH*NSRC)                 // 32768
#define OFF_HDST  0
#define OFF_ASRC  (OFF_HDST + SZ_HDST)
#define OFF_ADST  (OFF_ASRC + SZ_A)
#define OFF_SORTD (OFF_ADST + SZ_A)
#define OFF_PRE1  (OFF_SORTD + SZ_A)
#define OFF_PRE2  (OFF_PRE1 + SZ_HDST)
#define OFF_ZP1   (OFF_PRE2 + SZ_HDST)
#define OFF_ZP2   (OFF_ZP1 + SZ_A)
#define OFF_T1    (OFF_ZP2 + SZ_A)
#define OFF_T2    (OFF_T1 + BB*HH*OUTD)
#define OFF_TZ1   (OFF_T2 + BB*HH*OUTD)
#define OFF_TZ2   (OFF_TZ1 + BB*HH)
#define OFF_FOUT  (OFF_TZ2 + BB*HH)

// K1: per-head projection h = feat @ W[h], plus a = sum_o tanh(h)*w_a[h][o].
// grid: (s, b, h, tile64) = 2*4*4*32 = 1024 blocks, 256 threads.
__global__ __launch_bounds__(256) void k1_proj(const float* __restrict__ feat_src,
                                               const float* __restrict__ feat_dst,
                                               const float* __restrict__ W,
                                               const float* __restrict__ w_src,
                                               const float* __restrict__ w_dst,
                                               float* __restrict__ ws) {
    __shared__ float lds[16384];   // 64KB: feat tile [64][256], later reused for h tile
    int bid = blockIdx.x;
    int t = bid & 31; int h = (bid >> 5) & 3; int b = (bid >> 7) & 3; int s = bid >> 9;
    const float* feat = s ? feat_dst : feat_src;
    const float* wa   = (s ? w_dst : w_src) + h * OUTD;
    int r0 = t * 64;
    int tid = threadIdx.x;
    const float* fbase = feat + ((size_t)b * NSRC + r0) * IND;
    #pragma unroll 4
    for (int it = 0; it < 64; ++it) {
        int lin = it * 256 + tid;
        lds[lin] = fbase[lin];
    }
    __syncthreads();
    int tx = tid & 15, ty = tid >> 4;       // cols tx*4..+4, rows ty*4..+4
    const float* Wh = W + (size_t)h * IND * OUTD;
    float acc[4][4];
    #pragma unroll
    for (int i = 0; i < 4; ++i)
        #pragma unroll
        for (int j = 0; j < 4; ++j) acc[i][j] = 0.f;
    for (int k = 0; k < IND; ++k) {
        float4 wv = *(const float4*)(Wh + k * 64 + tx * 4);
        #pragma unroll
        for (int i = 0; i < 4; ++i) {
            float fv = lds[(ty * 4 + i) * 256 + k];
            acc[i][0] += fv * wv.x;
            acc[i][1] += fv * wv.y;
            acc[i][2] += fv * wv.z;
            acc[i][3] += fv * wv.w;
        }
    }
    __syncthreads();
    // write h tile into lds with stride 65
    #pragma unroll
    for (int i = 0; i < 4; ++i)
        #pragma unroll
        for (int j = 0; j < 4; ++j)
            lds[(ty * 4 + i) * 65 + tx * 4 + j] = acc[i][j];
    __syncthreads();
    if (s) {  // store h_dst tile
        float* hd = ws + OFF_HDST + ((size_t)(b * HH + h) * NDST + r0) * OUTD;
        #pragma unroll 4
        for (int it = 0; it < 16; ++it) {
            int lin = it * 256 + tid;
            int r = lin >> 6, c = lin & 63;
            hd[lin] = lds[r * 65 + c];
        }
    }
    // a-reduction: a[r] = sum_c tanh(h[r][c]) * wa[c]
    {
        int row = tid >> 2, part = tid & 3;
        float sum = 0.f;
        #pragma unroll
        for (int cc = 0; cc < 16; ++cc) {
            int c = part * 16 + cc;
            sum += tanhf(lds[row * 65 + c]) * wa[c];
        }
        lds[4160 + row * 4 + part] = sum;
    }
    __syncthreads();
    if (tid < 64) {
        float a = lds[4160 + tid * 4] + lds[4160 + tid * 4 + 1]
                + lds[4160 + tid * 4 + 2] + lds[4160 + tid * 4 + 3];
        float* ap = ws + (s ? OFF_ADST : OFF_ASRC);
        ap[(b * HH + h) * NSRC + r0 + tid] = a;
    }
}

// K2: per (b,h): sort a_dst ascending, build prefix sums of e^d*h and e^{0.2d}*h.
// grid: 16 blocks, 256 threads.
__global__ __launch_bounds__(256) void k2_prefix(float* __restrict__ ws) {
    __shared__ float keys[2048];
    __shared__ int   idxs[2048];
    __shared__ float w1s[2048], w2s[2048];
    __shared__ float T1c[4][64], T2c[4][64];
    __shared__ float Zc1[4], Zc2[4];
    int bh = blockIdx.x;
    int tid = threadIdx.x;
    const float* ad = ws + OFF_ADST + bh * NDST;
    for (int i = tid; i < 2048; i += 256) { keys[i] = ad[i]; idxs[i] = i; }
    __syncthreads();
    for (int k = 2; k <= 2048; k <<= 1) {
        for (int j = k >> 1; j > 0; j >>= 1) {
            for (int i = tid; i < 2048; i += 256) {
                int ixj = i ^ j;
                if (ixj > i) {
                    bool up = (i & k) == 0;
                    float a = keys[i], bv = keys[ixj];
                    if ((a > bv) == up) {
                        keys[i] = bv; keys[ixj] = a;
                        int ti = idxs[i]; idxs[i] = idxs[ixj]; idxs[ixj] = ti;
                    }
                }
            }
            __syncthreads();
        }
    }
    for (int i = tid; i < 2048; i += 256) {
        float d = keys[i];
        w1s[i] = expf(d);
        w2s[i] = expf(ALPHA * d);
        ws[OFF_SORTD + bh * 2048 + i] = d;
    }
    __syncthreads();
    int c = tid >> 6, o = tid & 63;
    const float* hd = ws + OFF_HDST + (size_t)bh * NDST * OUTD;
    // pass 1: chunk totals
    float t1 = 0.f, t2 = 0.f, z1 = 0.f, z2 = 0.f;
    for (int ii = 0; ii < 512; ++ii) {
        int i = c * 512 + ii;
        int m = idxs[i];
        float hv = hd[m * 64 + o];
        t1 += w1s[i] * hv; t2 += w2s[i] * hv;
        z1 += w1s[i];      z2 += w2s[i];
    }
    T1c[c][o] = t1; T2c[c][o] = t2;
    if (o == 0) { Zc1[c] = z1; Zc2[c] = z2; }
    __syncthreads();
    float a1 = 0.f, a2 = 0.f, zz1 = 0.f, zz2 = 0.f;
    for (int cc = 0; cc < c; ++cc) {
        a1 += T1c[cc][o]; a2 += T2c[cc][o];
        zz1 += Zc1[cc];   zz2 += Zc2[cc];
    }
    float* P1 = ws + OFF_PRE1 + (size_t)bh * NDST * OUTD;
    float* P2 = ws + OFF_PRE2 + (size_t)bh * NDST * OUTD;
    float* ZP1 = ws + OFF_ZP1 + bh * NDST;
    float* ZP2 = ws + OFF_ZP2 + bh * NDST;
    for (int ii = 0; ii < 512; ++ii) {
        int i = c * 512 + ii;
        P1[(size_t)i * 64 + o] = a1;
        P2[(size_t)i * 64 + o] = a2;
        if (o == 0) { ZP1[i] = zz1; ZP2[i] = zz2; }
        int m = idxs[i];
        float hv = hd[m * 64 + o];
        a1 += w1s[i] * hv; a2 += w2s[i] * hv;
        zz1 += w1s[i];     zz2 += w2s[i];
    }
    if (c == 3) {
        ws[OFF_T1 + bh * 64 + o] = a1;
        ws[OFF_T2 + bh * 64 + o] = a2;
        if (o == 0) { ws[OFF_TZ1 + bh] = zz1; ws[OFF_TZ2 + bh] = zz2; }
    }
}

// K3: per (b,h,n): binary search threshold, combine prefix/suffix sums.
// grid: B*H*N/4 = 8192 blocks, 256 threads (one wave per n-row, lane=o).
__global__ __launch_bounds__(256) void k3_out(const float* __restrict__ bias,
                                              float* __restrict__ ws) {
    int tid = threadIdx.x;
    int wid = blockIdx.x * 4 + (tid >> 6);
    int o = tid & 63;
    int n = wid & 2047;
    int bh = wid >> 11;
    float t = ws[OFF_ASRC + bh * 2048 + n];
    const float* sd = ws + OFF_SORTD + bh * 2048;
    float th = -t;
    int lo = 0, hi = 2048;
    while (lo < hi) {
        int mid = (lo + hi) >> 1;
        if (sd[mid] <= th) lo = mid + 1; else hi = mid;
    }
    int j = lo;
    float T1v = ws[OFF_T1 + bh * 64 + o];
    float T2v = ws[OFF_T2 + bh * 64 + o];
    float tz1 = ws[OFF_TZ1 + bh], tz2 = ws[OFF_TZ2 + bh];
    float p1, p2, zp1, zp2;
    if (j < 2048) {
        p1 = ws[OFF_PRE1 + ((size_t)bh * 2048 + j) * 64 + o];
        p2 = ws[OFF_PRE2 + ((size_t)bh * 2048 + j) * 64 + o];
        zp1 = ws[OFF_ZP1 + bh * 2048 + j];
        zp2 = ws[OFF_ZP2 + bh * 2048 + j];
    } else { p1 = T1v; p2 = T2v; zp1 = tz1; zp2 = tz2; }
    float et = expf(t), et2 = expf(ALPHA * t);
    float num = et * (T1v - p1) + et2 * p2;
    float den = et * (tz1 - zp1) + et2 * zp2;
    float val = num / den + bias[o];
    int b = bh >> 2, h = bh & 3;
    ws[OFF_FOUT + ((size_t)(b * NSRC + n)) * 256 + h * 64 + o] = val;
}

// K4: gate = sigmoid(feat_src @ Hw^T + Hb); out = gate*elu(feat_out) + (1-gate)*feat_src
// grid: 8192/32 = 256 blocks, 256 threads. 32 rows per block.
__global__ __launch_bounds__(256) void k4_gate(const float* __restrict__ feat_src,
                                               const float* __restrict__ Hw,
                                               const float* __restrict__ Hb,
                                               const float* __restrict__ ws,
                                               float* __restrict__ out) {
    __shared__ float featL[32 * 256];   // 32KB
    __shared__ float HwL[256 * 65];     // 66.56KB (stride-65 pad, conflict-free)
    int bid = blockIdx.x;
    int tid = threadIdx.x;
    int brow = bid * 32;                // global row in [0, 8192)
    #pragma unroll 4
    for (int it = 0; it < 32; ++it) {
        int lin = it * 256 + tid;
        featL[lin] = feat_src[(size_t)brow * 256 + lin];
    }
    int tx = tid & 31, ty = tid >> 5;   // cols tx+32*j, rows ty+8*i
    float acc[4][8];
    #pragma unroll
    for (int i = 0; i < 4; ++i)
        #pragma unroll
        for (int j = 0; j < 8; ++j) acc[i][j] = 0.f;
    for (int kt = 0; kt < 4; ++kt) {
        __syncthreads();
        #pragma unroll 4
        for (int it = 0; it < 64; ++it) {
            int lin = it * 256 + tid;
            int c = lin >> 6, kk = lin & 63;
            HwL[c * 65 + kk] = Hw[(size_t)c * 256 + kt * 64 + kk];
        }
        __syncthreads();
        for (int kk = 0; kk < 64; ++kk) {
            int k = kt * 64 + kk;
            float fv[4], wv[8];
            #pragma unroll
            for (int i = 0; i < 4; ++i) fv[i] = featL[(ty + 8 * i) * 256 + k];
            #pragma unroll
            for (int j = 0; j < 8; ++j) wv[j] = HwL[(tx + 32 * j) * 65 + kk];
            #pragma unroll
            for (int i = 0; i < 4; ++i)
                #pragma unroll
                for (int j = 0; j < 8; ++j) acc[i][j] += fv[i] * wv[j];
        }
    }
    #pragma unroll
    for (int i = 0; i < 4; ++i) {
        int r = ty + 8 * i;
        #pragma unroll
        for (int j = 0; j < 8; ++j) {
            int c = tx + 32 * j;
            float x = acc[i][j] + Hb[c];
            float g = 1.f / (1.f + expf(-x));
            float fo = ws[OFF_FOUT + (size_t)(brow + r) * 256 + c];
            float e = fo > 0.f ? fo : expm1f(fo);
            float fs = featL[r * 256 + c];
            out[(size_t)(brow + r) * 256 + c] = g * e + (1.f - g) * fs;
        }
    }
}

extern "C" void kernel_launch(void* const* d_in, const int* in_sizes, int n_in,
                              void* d_out, int out_size, void* d_ws, size_t ws_size,
                              hipStream_t stream) {
    const float* feat_src = (const float*)d_in[0];
    const float* feat_dst = (const float*)d_in[1];
    const float* W        = (const float*)d_in[2];
    const float* bias     = (const float*)d_in[3];
    const float* w_src    = (const float*)d_in[4];
    const float* w_dst    = (const float*)d_in[5];
    const float* Hw       = (const float*)d_in[6];
    const float* Hb       = (const float*)d_in[7];
    float* out = (float*)d_out;
    float* ws  = (float*)d_ws;

    k1_proj<<<1024, 256, 0, stream>>>(feat_src, feat_dst, W, w_src, w_dst, ws);
    k2_prefix<<<16, 256, 0, stream>>>(ws);
    k3_out<<<8192, 256, 0, stream>>>(bias, ws);
    k4_gate<<<256, 256, 0, stream>>>(feat_src, Hw, Hb, ws, out);
}

// Round 2
// 159.396 us; speedup vs baseline: 1.9863x; 1.9863x over previous
//
#include <hip/hip_runtime.h>
#include <math.h>

#define BB 4
#define HH 4
#define NSRC 2048
#define NDST 2048
#define IND 256
#define OUTD 64
#define ALPHA 0.2f
#define NCH 128           // 16-element chunks per (b,h)

// workspace layout (float offsets). FOUT aliases HDST (HDST dead after k2b).
#define SZ_HD (BB*HH*NDST*OUTD)   // 2097152
#define SZ_A  (BB*HH*NDST)        // 32768
#define OFF_HDST  0
#define OFF_FOUT  0
#define OFF_ASRC  2097152
#define OFF_ADST  2129920
#define OFF_SORTD 2162688
#define OFF_IDX   2195456
#define OFF_W1S   2228224
#define OFF_W2S   2260992
#define OFF_V1    2293760
#define OFF_V2    4390912
#define OFF_C1    6488064
#define OFF_C2    6619136
#define OFF_CZ1   6750208
#define OFF_CZ2   6752256
#define OFF_T1    6754304
#define OFF_T2    6755328
#define OFF_TZ1   6756352
#define OFF_TZ2   6756368

__device__ __forceinline__ float fast_tanh(float x) {
    float e = __expf(2.f * x);
    return 1.f - 2.f / (e + 1.f);
}

// K1: per-head projection h = feat @ W[h], plus a = sum_o tanh(h)*w_a[h][o].
// grid: (s, b, h, tile64) = 1024 blocks, 256 threads.
__global__ __launch_bounds__(256) void k1_proj(const float* __restrict__ feat_src,
                                               const float* __restrict__ feat_dst,
                                               const float* __restrict__ W,
                                               const float* __restrict__ w_src,
                                               const float* __restrict__ w_dst,
                                               float* __restrict__ ws) {
    __shared__ float lds[16384];   // 64KB: feat tile [64][256], later reused for h tile
    int bid = blockIdx.x;
    int t = bid & 31; int h = (bid >> 5) & 3; int b = (bid >> 7) & 3; int s = bid >> 9;
    const float* feat = s ? feat_dst : feat_src;
    const float* wa   = (s ? w_dst : w_src) + h * OUTD;
    int r0 = t * 64;
    int tid = threadIdx.x;
    const float4* fbase = (const float4*)(feat + ((size_t)b * NSRC + r0) * IND);
    #pragma unroll 4
    for (int it = 0; it < 16; ++it)
        ((float4*)lds)[it * 256 + tid] = fbase[it * 256 + tid];
    __syncthreads();
    int tx = tid & 15, ty = tid >> 4;       // cols tx*4..+4, rows ty*4..+4
    const float* Wh = W + (size_t)h * IND * OUTD;
    float acc[4][4];
    #pragma unroll
    for (int i = 0; i < 4; ++i)
        #pragma unroll
        for (int j = 0; j < 4; ++j) acc[i][j] = 0.f;
    for (int k = 0; k < IND; k += 4) {
        float4 fv4[4];
        #pragma unroll
        for (int i = 0; i < 4; ++i)
            fv4[i] = *(const float4*)&lds[(ty * 4 + i) * 256 + k];
        #pragma unroll
        for (int kk = 0; kk < 4; ++kk) {
            float4 wv = *(const float4*)(Wh + (k + kk) * 64 + tx * 4);
            #pragma unroll
            for (int i = 0; i < 4; ++i) {
                float fv = kk == 0 ? fv4[i].x : kk == 1 ? fv4[i].y : kk == 2 ? fv4[i].z : fv4[i].w;
                acc[i][0] += fv * wv.x;
                acc[i][1] += fv * wv.y;
                acc[i][2] += fv * wv.z;
                acc[i][3] += fv * wv.w;
            }
        }
    }
    __syncthreads();
    #pragma unroll
    for (int i = 0; i < 4; ++i)
        #pragma unroll
        for (int j = 0; j < 4; ++j)
            lds[(ty * 4 + i) * 65 + tx * 4 + j] = acc[i][j];
    __syncthreads();
    if (s) {  // store h_dst tile
        float* hd = ws + OFF_HDST + ((size_t)(b * HH + h) * NDST + r0) * OUTD;
        #pragma unroll 4
        for (int it = 0; it < 16; ++it) {
            int lin = it * 256 + tid;
            int r = lin >> 6, c = lin & 63;
            hd[lin] = lds[r * 65 + c];
        }
    }
    // a-reduction: a[r] = sum_c tanh(h[r][c]) * wa[c]
    {
        int row = tid >> 2, part = tid & 3;
        float sum = 0.f;
        #pragma unroll
        for (int cc = 0; cc < 16; ++cc) {
            int c = part * 16 + cc;
            sum += fast_tanh(lds[row * 65 + c]) * wa[c];
        }
        lds[4160 + row * 4 + part] = sum;
    }
    __syncthreads();
    if (tid < 64) {
        float a = lds[4160 + tid * 4] + lds[4160 + tid * 4 + 1]
                + lds[4160 + tid * 4 + 2] + lds[4160 + tid * 4 + 3];
        float* ap = ws + (s ? OFF_ADST : OFF_ASRC);
        ap[(b * HH + h) * NSRC + r0 + tid] = a;
    }
}

// K2a: per (b,h) bitonic sort of a_dst (ascending). One compare-exchange per
// thread per stage. grid: 16 blocks, 1024 threads.
__global__ __launch_bounds__(1024) void k2a_sort(float* __restrict__ ws) {
    __shared__ float keys[2048];
    __shared__ int   idxs[2048];
    int bh = blockIdx.x;
    int tid = threadIdx.x;
    const float* ad = ws + OFF_ADST + bh * NDST;
    keys[tid] = ad[tid];           idxs[tid] = tid;
    keys[tid + 1024] = ad[tid + 1024]; idxs[tid + 1024] = tid + 1024;
    __syncthreads();
    for (int k = 2; k <= 2048; k <<= 1) {
        for (int j = k >> 1; j > 0; j >>= 1) {
            int i = ((tid & ~(j - 1)) << 1) | (tid & (j - 1));
            int p = i | j;
            bool up = (i & k) == 0;
            float a = keys[i], bv = keys[p];
            if ((a > bv) == up) {
                keys[i] = bv; keys[p] = a;
                int ti = idxs[i]; idxs[i] = idxs[p]; idxs[p] = ti;
            }
            __syncthreads();
        }
    }
    int* idxp = (int*)(ws + OFF_IDX) + bh * NDST;
    float* sd = ws + OFF_SORTD + bh * NDST;
    float* w1 = ws + OFF_W1S + bh * NDST;
    float* w2 = ws + OFF_W2S + bh * NDST;
    #pragma unroll
    for (int r = 0; r < 2; ++r) {
        int i = tid + r * 1024;
        float d = keys[i];
        sd[i] = d;
        idxp[i] = idxs[i];
        w1[i] = expf(d);
        w2[i] = expf(ALPHA * d);
    }
}

// K2b: gather+scale in sorted order, V1=e^d*h, V2=e^{0.2d}*h, chunk-16 totals.
// grid: 16 bh * 16 = 256 blocks, 256 threads (wave q handles 2 chunks).
__global__ __launch_bounds__(256) void k2b_gather(float* __restrict__ ws) {
    int bh = blockIdx.x >> 4, blk = blockIdx.x & 15;
    int tid = threadIdx.x;
    int o = tid & 63, q = tid >> 6;
    const int* idxp = (const int*)(ws + OFF_IDX) + bh * NDST;
    const float* w1s = ws + OFF_W1S + bh * NDST;
    const float* w2s = ws + OFF_W2S + bh * NDST;
    const float* hd = ws + OFF_HDST + (size_t)bh * NDST * OUTD;
    float* V1 = ws + OFF_V1 + (size_t)bh * NDST * OUTD;
    float* V2 = ws + OFF_V2 + (size_t)bh * NDST * OUTD;
    #pragma unroll
    for (int cc = 0; cc < 2; ++cc) {
        int chunk = blk * 8 + q * 2 + cc;
        float c1 = 0.f, c2 = 0.f, cz1 = 0.f, cz2 = 0.f;
        #pragma unroll 4
        for (int ii = 0; ii < 16; ++ii) {
            int i = chunk * 16 + ii;
            int m = idxp[i];
            float w1 = w1s[i], w2 = w2s[i];
            float hv = hd[m * 64 + o];
            float v1 = w1 * hv, v2 = w2 * hv;
            V1[(size_t)i * 64 + o] = v1;
            V2[(size_t)i * 64 + o] = v2;
            c1 += v1; c2 += v2; cz1 += w1; cz2 += w2;
        }
        ws[OFF_C1 + (bh * NCH + chunk) * 64 + o] = c1;
        ws[OFF_C2 + (bh * NCH + chunk) * 64 + o] = c2;
        if (o == 0) {
            ws[OFF_CZ1 + bh * NCH + chunk] = cz1;
            ws[OFF_CZ2 + bh * NCH + chunk] = cz2;
        }
    }
}

// K2c: in-place exclusive scan of chunk totals over the 128 chunks per (bh,o).
// grid: 16 blocks, 128 threads (wave0 -> C1, wave1 -> C2).
__global__ __launch_bounds__(128) void k2c_scan(float* __restrict__ ws) {
    int bh = blockIdx.x;
    int tid = threadIdx.x;
    int o = tid & 63, w = tid >> 6;
    float* C = ws + (w == 0 ? OFF_C1 : OFF_C2) + bh * NCH * 64;
    float run = 0.f;
    for (int c = 0; c < NCH; ++c) {
        float v = C[c * 64 + o];
        C[c * 64 + o] = run;
        run += v;
    }
    ws[(w == 0 ? OFF_T1 : OFF_T2) + bh * 64 + o] = run;
    if (o == 0) {
        float* CZ = ws + (w == 0 ? OFF_CZ1 : OFF_CZ2) + bh * NCH;
        float rz = 0.f;
        for (int c = 0; c < NCH; ++c) {
            float v = CZ[c];
            CZ[c] = rz;
            rz += v;
        }
        ws[(w == 0 ? OFF_TZ1 : OFF_TZ2) + bh] = rz;
    }
}

// K3: per (b,h,n): binary search threshold, coarse prefix + remainder combine.
// grid: 8192 blocks, 256 threads (one wave per query row, lane=o).
__global__ __launch_bounds__(256) void k3_out(const float* __restrict__ bias,
                                              float* __restrict__ ws) {
    int tid = threadIdx.x;
    int wid = blockIdx.x * 4 + (tid >> 6);
    int o = tid & 63;
    int n = wid & 2047;
    int bh = wid >> 11;
    float t = ws[OFF_ASRC + bh * 2048 + n];
    const float* sd = ws + OFF_SORTD + bh * 2048;
    float th = -t;
    int lo = 0, hi = 2048;
    while (lo < hi) {
        int mid = (lo + hi) >> 1;
        if (sd[mid] <= th) lo = mid + 1; else hi = mid;
    }
    int j = lo;                                   // count of d <= -t (lower branch)
    int c = j >> 4; if (c > NCH - 1) c = NCH - 1;
    int i0 = c << 4;
    float p1 = ws[OFF_C1 + (bh * NCH + c) * 64 + o];
    float p2 = ws[OFF_C2 + (bh * NCH + c) * 64 + o];
    float zp1 = ws[OFF_CZ1 + bh * NCH + c];
    float zp2 = ws[OFF_CZ2 + bh * NCH + c];
    const float* V1 = ws + OFF_V1 + (size_t)bh * NDST * OUTD;
    const float* V2 = ws + OFF_V2 + (size_t)bh * NDST * OUTD;
    const float* w1s = ws + OFF_W1S + bh * NDST;
    const float* w2s = ws + OFF_W2S + bh * NDST;
    for (int i = i0; i < j; ++i) {
        p1 += V1[(size_t)i * 64 + o];
        p2 += V2[(size_t)i * 64 + o];
        zp1 += w1s[i];
        zp2 += w2s[i];
    }
    float T1v = ws[OFF_T1 + bh * 64 + o];
    float T2v = ws[OFF_T2 + bh * 64 + o];
    float tz1 = ws[OFF_TZ1 + bh], tz2 = ws[OFF_TZ2 + bh];
    float et = __expf(t), et2 = __expf(ALPHA * t);
    float num = et * (T1v - p1) + et2 * p2;
    float den = et * (tz1 - zp1) + et2 * zp2;
    float val = num / den + bias[o];
    ws[OFF_FOUT + ((size_t)(bh >> 2) * NSRC + n) * 256 + (bh & 3) * 64 + o] = val;
}

// K4: gate = sigmoid(feat_src @ Hw^T + Hb); out = gate*elu(feat_out)+(1-gate)*feat_src
// grid: 256 row-tiles * 2 col-halves = 512 blocks, 256 threads. 32x128 tile.
__global__ __launch_bounds__(256) void k4_gate(const float* __restrict__ feat_src,
                                               const float* __restrict__ Hw,
                                               const float* __restrict__ Hb,
                                               const float* __restrict__ ws,
                                               float* __restrict__ out) {
    __shared__ float featL[32 * 256];   // 32KB
    __shared__ float HwL[128 * 68];     // 34.8KB (stride-68: 16B-aligned, 4-way max)
    int bid = blockIdx.x;
    int tid = threadIdx.x;
    int brow = (bid >> 1) * 32;
    int bcol = (bid & 1) * 128;
    const float4* fb = (const float4*)(feat_src + (size_t)brow * 256);
    #pragma unroll
    for (int it = 0; it < 8; ++it)
        ((float4*)featL)[it * 256 + tid] = fb[it * 256 + tid];
    int tx = tid & 31, ty = tid >> 5;   // cols bcol+tx+32j, rows ty+8i
    float acc[4][4];
    #pragma unroll
    for (int i = 0; i < 4; ++i)
        #pragma unroll
        for (int j = 0; j < 4; ++j) acc[i][j] = 0.f;
    for (int kt = 0; kt < 4; ++kt) {
        __syncthreads();
        #pragma unroll
        for (int it = 0; it < 8; ++it) {
            int f4 = it * 256 + tid;          // 0..2047
            int cc = f4 >> 4, q = f4 & 15;
            *(float4*)&HwL[cc * 68 + q * 4] =
                *(const float4*)&Hw[(size_t)(bcol + cc) * 256 + kt * 64 + q * 4];
        }
        __syncthreads();
        for (int kk = 0; kk < 64; kk += 4) {
            float4 fv4[4], wv4[4];
            #pragma unroll
            for (int i = 0; i < 4; ++i)
                fv4[i] = *(const float4*)&featL[(ty + 8 * i) * 256 + kt * 64 + kk];
            #pragma unroll
            for (int j = 0; j < 4; ++j)
                wv4[j] = *(const float4*)&HwL[(tx + 32 * j) * 68 + kk];
            #pragma unroll
            for (int i = 0; i < 4; ++i)
                #pragma unroll
                for (int j = 0; j < 4; ++j) {
                    acc[i][j] += fv4[i].x * wv4[j].x;
                    acc[i][j] += fv4[i].y * wv4[j].y;
                    acc[i][j] += fv4[i].z * wv4[j].z;
                    acc[i][j] += fv4[i].w * wv4[j].w;
                }
        }
    }
    #pragma unroll
    for (int i = 0; i < 4; ++i) {
        int r = ty + 8 * i;
        #pragma unroll
        for (int j = 0; j < 4; ++j) {
            int c = bcol + tx + 32 * j;
            float x = acc[i][j] + Hb[c];
            float g = 1.f / (1.f + __expf(-x));
            float fo = ws[OFF_FOUT + (size_t)(brow + r) * 256 + c];
            float e = fo > 0.f ? fo : expm1f(fo);
            float fs = featL[r * 256 + c];
            out[(size_t)(brow + r) * 256 + c] = g * e + (1.f - g) * fs;
        }
    }
}

extern "C" void kernel_launch(void* const* d_in, const int* in_sizes, int n_in,
                              void* d_out, int out_size, void* d_ws, size_t ws_size,
                              hipStream_t stream) {
    const float* feat_src = (const float*)d_in[0];
    const float* feat_dst = (const float*)d_in[1];
    const float* W        = (const float*)d_in[2];
    const float* bias     = (const float*)d_in[3];
    const float* w_src    = (const float*)d_in[4];
    const float* w_dst    = (const float*)d_in[5];
    const float* Hw       = (const float*)d_in[6];
    const float* Hb       = (const float*)d_in[7];
    float* out = (float*)d_out;
    float* ws  = (float*)d_ws;

    k1_proj<<<1024, 256, 0, stream>>>(feat_src, feat_dst, W, w_src, w_dst, ws);
    k2a_sort<<<16, 1024, 0, stream>>>(ws);
    k2b_gather<<<256, 256, 0, stream>>>(ws);
    k2c_scan<<<16, 128, 0, stream>>>(ws);
    k3_out<<<8192, 256, 0, stream>>>(bias, ws);
    k4_gate<<<512, 256, 0, stream>>>(feat_src, Hw, Hb, ws, out);
}

// Round 3
// 132.129 us; speedup vs baseline: 2.3962x; 1.2064x over previous
//
#include <hip/hip_runtime.h>
#include <math.h>

typedef unsigned int  uint32;
typedef unsigned short ushort16;
typedef __attribute__((ext_vector_type(8))) short bf16x8;
typedef __attribute__((ext_vector_type(4))) float f32x4;

#define BB 4
#define HH 4
#define NSRC 2048
#define NDST 2048
#define IND 256
#define OUTD 64
#define ALPHA 0.2f
#define NCH 128           // 16-element chunks per (b,h)

// workspace layout (float offsets). FOUT aliases HDST (HDST dead after k2b).
#define OFF_HDST  0
#define OFF_FOUT  0
#define OFF_ASRC  2097152
#define OFF_ADST  2129920
#define OFF_SORTD 2162688
#define OFF_IDX   2195456
#define OFF_W1S   2228224
#define OFF_W2S   2260992
#define OFF_V1    2293760
#define OFF_V2    4390912
#define OFF_C1    6488064
#define OFF_C2    6619136
#define OFF_CZ1   6750208
#define OFF_CZ2   6752256
#define OFF_T1    6754304
#define OFF_T2    6755328
#define OFF_TZ1   6756352
#define OFF_TZ2   6756368
#define OFF_WFH   6756384   // W frags hi: 65536 bf16 = 32768 float units
#define OFF_WFL   6789152   // W frags lo

__device__ __forceinline__ float fast_tanh(float x) {
    float e = __expf(2.f * x);
    return 1.f - 2.f / (e + 1.f);
}

__device__ __forceinline__ uint32 f32_to_bf16_rne(float x) {
    uint32 u = __float_as_uint(x);
    return (u + 0x7fffu + ((u >> 16) & 1u)) >> 16;
}

// K0: pre-pack W[h][k][o] into MFMA B-fragment order, split bf16 hi/lo.
// Frag (h, ks, ni): lane l holds B[k = ks*32 + (l>>4)*8 + j][col = ni*16 + (l&15)].
// grid: 32 blocks, 256 threads (8192 lane-slots).
__global__ __launch_bounds__(256) void k0_wf(const float* __restrict__ W,
                                             float* __restrict__ ws) {
    int g = blockIdx.x * 256 + threadIdx.x;    // 0..8191
    int l = g & 63, ni = (g >> 6) & 3, ks = (g >> 8) & 7, h = g >> 11;
    int col = ni * 16 + (l & 15);
    int k0 = ks * 32 + (l >> 4) * 8;
    unsigned short hs[8], lsv[8];
    #pragma unroll
    for (int j = 0; j < 8; ++j) {
        float w = W[h * 16384 + (k0 + j) * 64 + col];
        uint32 hb = f32_to_bf16_rne(w);
        float hf = __uint_as_float(hb << 16);
        uint32 lb = f32_to_bf16_rne(w - hf);
        hs[j] = (unsigned short)hb; lsv[j] = (unsigned short)lb;
    }
    unsigned short* wfh = (unsigned short*)(ws + OFF_WFH);
    unsigned short* wfl = (unsigned short*)(ws + OFF_WFL);
    int slab = ((h * 8 + ks) * 4 + ni) * 512 + l * 8;
    #pragma unroll
    for (int j = 0; j < 8; ++j) { wfh[slab + j] = hs[j]; wfl[slab + j] = lsv[j]; }
}

// K1: projection via MFMA, split-bf16 3-pass (hi*hi + hi*lo + lo*hi ~= fp32).
// Block: 64 rows x 4 heads; wave w = head w (64x64 out, K=256).
// grid: s(2) * b(4) * t(32) = 256 blocks, 256 threads.
__global__ __launch_bounds__(256) void k1_mfma(const float* __restrict__ feat_src,
                                               const float* __restrict__ feat_dst,
                                               const float* __restrict__ w_src,
                                               const float* __restrict__ w_dst,
                                               float* __restrict__ ws) {
    __shared__ __align__(16) unsigned short Ahi[64 * 256];   // 32KB, XOR-swizzled
    __shared__ __align__(16) unsigned short Alo[64 * 256];   // 32KB
    int bid = blockIdx.x;
    int t = bid & 31, b = (bid >> 5) & 3, s = bid >> 7;
    int tid = threadIdx.x;
    const float* feat = s ? feat_dst : feat_src;
    const float4* fb = (const float4*)(feat + ((size_t)b * 2048 + t * 64) * IND);
    // stage feat tile -> bf16 hi/lo in LDS (swizzle: byte ^= (row&7)<<4)
    #pragma unroll
    for (int it = 0; it < 16; ++it) {
        int f4 = it * 256 + tid;
        int row = f4 >> 6, c4 = f4 & 63;
        float4 v = fb[f4];
        float xs[4] = {v.x, v.y, v.z, v.w};
        uint32 hb[4], lb[4];
        #pragma unroll
        for (int j = 0; j < 4; ++j) {
            hb[j] = f32_to_bf16_rne(xs[j]);
            float hf = __uint_as_float(hb[j] << 16);
            lb[j] = f32_to_bf16_rne(xs[j] - hf);
        }
        uint2 hw, lw;
        hw.x = hb[0] | (hb[1] << 16); hw.y = hb[2] | (hb[3] << 16);
        lw.x = lb[0] | (lb[1] << 16); lw.y = lb[2] | (lb[3] << 16);
        int baddr = (row * 512 + c4 * 8) ^ ((row & 7) << 4);
        *(uint2*)((char*)Ahi + baddr) = hw;
        *(uint2*)((char*)Alo + baddr) = lw;
    }
    __syncthreads();
    int w = tid >> 6, l = tid & 63;
    int lr = l & 15, lq = l >> 4;
    f32x4 acc[4][4];
    #pragma unroll
    for (int mi = 0; mi < 4; ++mi)
        #pragma unroll
        for (int ni = 0; ni < 4; ++ni) acc[mi][ni] = (f32x4)0.f;
    const uint4* wfh = (const uint4*)(ws + OFF_WFH);
    const uint4* wfl = (const uint4*)(ws + OFF_WFL);
    for (int ks = 0; ks < 8; ++ks) {
        bf16x8 ah[4], al[4], bh[4], bl[4];
        #pragma unroll
        for (int mi = 0; mi < 4; ++mi) {
            int row = mi * 16 + lr;
            int baddr = (row * 512 + ks * 64 + lq * 16) ^ ((row & 7) << 4);
            ah[mi] = *(const bf16x8*)((const char*)Ahi + baddr);
            al[mi] = *(const bf16x8*)((const char*)Alo + baddr);
        }
        #pragma unroll
        for (int ni = 0; ni < 4; ++ni) {
            int idx = ((w * 8 + ks) * 4 + ni) * 64 + l;
            uint4 th_ = wfh[idx], tl_ = wfl[idx];
            bh[ni] = *(const bf16x8*)&th_;
            bl[ni] = *(const bf16x8*)&tl_;
        }
        #pragma unroll
        for (int mi = 0; mi < 4; ++mi)
            #pragma unroll
            for (int ni = 0; ni < 4; ++ni) {
                acc[mi][ni] = __builtin_amdgcn_mfma_f32_16x16x32_bf16(ah[mi], bh[ni], acc[mi][ni], 0, 0, 0);
                acc[mi][ni] = __builtin_amdgcn_mfma_f32_16x16x32_bf16(ah[mi], bl[ni], acc[mi][ni], 0, 0, 0);
                acc[mi][ni] = __builtin_amdgcn_mfma_f32_16x16x32_bf16(al[mi], bh[ni], acc[mi][ni], 0, 0, 0);
            }
    }
    // epilogue: C row = mi*16 + lq*4 + r, col = ni*16 + lr
    if (s) {
        float* hd = ws + OFF_HDST + ((size_t)(b * HH + w) * NDST + t * 64) * OUTD;
        #pragma unroll
        for (int mi = 0; mi < 4; ++mi)
            #pragma unroll
            for (int ni = 0; ni < 4; ++ni)
                #pragma unroll
                for (int r = 0; r < 4; ++r)
                    hd[(mi * 16 + lq * 4 + r) * 64 + ni * 16 + lr] = acc[mi][ni][r];
    }
    const float* wa = (s ? w_dst : w_src) + w * OUTD;
    float wa_v[4];
    #pragma unroll
    for (int ni = 0; ni < 4; ++ni) wa_v[ni] = wa[ni * 16 + lr];
    float* ap = ws + (s ? OFF_ADST : OFF_ASRC) + (b * HH + w) * NSRC + t * 64;
    #pragma unroll
    for (int mi = 0; mi < 4; ++mi)
        #pragma unroll
        for (int r = 0; r < 4; ++r) {
            float p = 0.f;
            #pragma unroll
            for (int ni = 0; ni < 4; ++ni) p += fast_tanh(acc[mi][ni][r]) * wa_v[ni];
            p += __shfl_xor(p, 1); p += __shfl_xor(p, 2);
            p += __shfl_xor(p, 4); p += __shfl_xor(p, 8);
            if (lr == 0) ap[mi * 16 + lq * 4 + r] = p;
        }
}

// K2a: per (b,h) bitonic sort of a_dst (ascending). grid: 16 blocks, 1024 threads.
__global__ __launch_bounds__(1024) void k2a_sort(float* __restrict__ ws) {
    __shared__ float keys[2048];
    __shared__ int   idxs[2048];
    int bh = blockIdx.x;
    int tid = threadIdx.x;
    const float* ad = ws + OFF_ADST + bh * NDST;
    keys[tid] = ad[tid];           idxs[tid] = tid;
    keys[tid + 1024] = ad[tid + 1024]; idxs[tid + 1024] = tid + 1024;
    __syncthreads();
    for (int k = 2; k <= 2048; k <<= 1) {
        for (int j = k >> 1; j > 0; j >>= 1) {
            int i = ((tid & ~(j - 1)) << 1) | (tid & (j - 1));
            int p = i | j;
            bool up = (i & k) == 0;
            float a = keys[i], bv = keys[p];
            if ((a > bv) == up) {
                keys[i] = bv; keys[p] = a;
                int ti = idxs[i]; idxs[i] = idxs[p]; idxs[p] = ti;
            }
            __syncthreads();
        }
    }
    int* idxp = (int*)(ws + OFF_IDX) + bh * NDST;
    float* sd = ws + OFF_SORTD + bh * NDST;
    float* w1 = ws + OFF_W1S + bh * NDST;
    float* w2 = ws + OFF_W2S + bh * NDST;
    #pragma unroll
    for (int r = 0; r < 2; ++r) {
        int i = tid + r * 1024;
        float d = keys[i];
        sd[i] = d;
        idxp[i] = idxs[i];
        w1[i] = expf(d);
        w2[i] = expf(ALPHA * d);
    }
}

// K2b: gather+scale in sorted order, V1=e^d*h, V2=e^{0.2d}*h, chunk-16 totals.
// grid: 256 blocks, 256 threads.
__global__ __launch_bounds__(256) void k2b_gather(float* __restrict__ ws) {
    int bh = blockIdx.x >> 4, blk = blockIdx.x & 15;
    int tid = threadIdx.x;
    int o = tid & 63, q = tid >> 6;
    const int* idxp = (const int*)(ws + OFF_IDX) + bh * NDST;
    const float* w1s = ws + OFF_W1S + bh * NDST;
    const float* w2s = ws + OFF_W2S + bh * NDST;
    const float* hd = ws + OFF_HDST + (size_t)bh * NDST * OUTD;
    float* V1 = ws + OFF_V1 + (size_t)bh * NDST * OUTD;
    float* V2 = ws + OFF_V2 + (size_t)bh * NDST * OUTD;
    #pragma unroll
    for (int cc = 0; cc < 2; ++cc) {
        int chunk = blk * 8 + q * 2 + cc;
        float c1 = 0.f, c2 = 0.f, cz1 = 0.f, cz2 = 0.f;
        #pragma unroll 4
        for (int ii = 0; ii < 16; ++ii) {
            int i = chunk * 16 + ii;
            int m = idxp[i];
            float w1 = w1s[i], w2 = w2s[i];
            float hv = hd[m * 64 + o];
            float v1 = w1 * hv, v2 = w2 * hv;
            V1[(size_t)i * 64 + o] = v1;
            V2[(size_t)i * 64 + o] = v2;
            c1 += v1; c2 += v2; cz1 += w1; cz2 += w2;
        }
        ws[OFF_C1 + (bh * NCH + chunk) * 64 + o] = c1;
        ws[OFF_C2 + (bh * NCH + chunk) * 64 + o] = c2;
        if (o == 0) {
            ws[OFF_CZ1 + bh * NCH + chunk] = cz1;
            ws[OFF_CZ2 + bh * NCH + chunk] = cz2;
        }
    }
}

// K2c: exclusive scan of chunk totals. grid: 16 blocks, 128 threads.
__global__ __launch_bounds__(128) void k2c_scan(float* __restrict__ ws) {
    int bh = blockIdx.x;
    int tid = threadIdx.x;
    int o = tid & 63, w = tid >> 6;
    float* C = ws + (w == 0 ? OFF_C1 : OFF_C2) + bh * NCH * 64;
    float run = 0.f;
    for (int c = 0; c < NCH; ++c) {
        float v = C[c * 64 + o];
        C[c * 64 + o] = run;
        run += v;
    }
    ws[(w == 0 ? OFF_T1 : OFF_T2) + bh * 64 + o] = run;
    if (o == 0) {
        float* CZ = ws + (w == 0 ? OFF_CZ1 : OFF_CZ2) + bh * NCH;
        float rz = 0.f;
        for (int c = 0; c < NCH; ++c) {
            float v = CZ[c];
            CZ[c] = rz;
            rz += v;
        }
        ws[(w == 0 ? OFF_TZ1 : OFF_TZ2) + bh] = rz;
    }
}

// K3: per (b,h,n): 64-ary ballot search + coarse prefix + remainder combine.
// grid: 8192 blocks, 256 threads (one wave per query row, lane=o).
__global__ __launch_bounds__(256) void k3_out(const float* __restrict__ bias,
                                              float* __restrict__ ws) {
    int tid = threadIdx.x;
    int wid = blockIdx.x * 4 + (tid >> 6);
    int o = tid & 63;
    int n = wid & 2047;
    int bh = wid >> 11;
    float t = ws[OFF_ASRC + bh * 2048 + n];
    const float* sd = ws + OFF_SORTD + bh * 2048;
    float th = -t;
    // coarse: lane o probes sd[o*32]
    unsigned long long m1 = __ballot(sd[o * 32] <= th);
    int cnt = __popcll(m1);
    int base = (cnt > 0 ? cnt - 1 : 0) * 32;
    unsigned long long m2 = __ballot(sd[base + (o & 31)] <= th);
    int j = base + __popcll(m2 & 0xFFFFFFFFull);   // count of d <= -t
    int c = j >> 4; if (c > NCH - 1) c = NCH - 1;
    int i0 = c << 4;
    float p1 = ws[OFF_C1 + (bh * NCH + c) * 64 + o];
    float p2 = ws[OFF_C2 + (bh * NCH + c) * 64 + o];
    float zp1 = ws[OFF_CZ1 + bh * NCH + c];
    float zp2 = ws[OFF_CZ2 + bh * NCH + c];
    const float* V1 = ws + OFF_V1 + (size_t)bh * NDST * OUTD;
    const float* V2 = ws + OFF_V2 + (size_t)bh * NDST * OUTD;
    const float* w1s = ws + OFF_W1S + bh * NDST;
    const float* w2s = ws + OFF_W2S + bh * NDST;
    for (int i = i0; i < j; ++i) {
        p1 += V1[(size_t)i * 64 + o];
        p2 += V2[(size_t)i * 64 + o];
        zp1 += w1s[i];
        zp2 += w2s[i];
    }
    float T1v = ws[OFF_T1 + bh * 64 + o];
    float T2v = ws[OFF_T2 + bh * 64 + o];
    float tz1 = ws[OFF_TZ1 + bh], tz2 = ws[OFF_TZ2 + bh];
    float et = __expf(t), et2 = __expf(ALPHA * t);
    float num = et * (T1v - p1) + et2 * p2;
    float den = et * (tz1 - zp1) + et2 * zp2;
    float val = num / den + bias[o];
    ws[OFF_FOUT + ((size_t)(bh >> 2) * NSRC + n) * 256 + (bh & 3) * 64 + o] = val;
}

// K4: gate = sigmoid(feat_src @ Hw^T + Hb); out = gate*elu(feat_out)+(1-gate)*feat_src
// grid: 512 blocks, 256 threads. 32x128 tile.
__global__ __launch_bounds__(256) void k4_gate(const float* __restrict__ feat_src,
                                               const float* __restrict__ Hw,
                                               const float* __restrict__ Hb,
                                               const float* __restrict__ ws,
                                               float* __restrict__ out) {
    __shared__ float featL[32 * 256];   // 32KB
    __shared__ float HwL[128 * 68];     // 34.8KB
    int bid = blockIdx.x;
    int tid = threadIdx.x;
    int brow = (bid >> 1) * 32;
    int bcol = (bid & 1) * 128;
    const float4* fb = (const float4*)(feat_src + (size_t)brow * 256);
    #pragma unroll
    for (int it = 0; it < 8; ++it)
        ((float4*)featL)[it * 256 + tid] = fb[it * 256 + tid];
    int tx = tid & 31, ty = tid >> 5;
    float acc[4][4];
    #pragma unroll
    for (int i = 0; i < 4; ++i)
        #pragma unroll
        for (int j = 0; j < 4; ++j) acc[i][j] = 0.f;
    for (int kt = 0; kt < 4; ++kt) {
        __syncthreads();
        #pragma unroll
        for (int it = 0; it < 8; ++it) {
            int f4 = it * 256 + tid;
            int cc = f4 >> 4, q = f4 & 15;
            *(float4*)&HwL[cc * 68 + q * 4] =
                *(const float4*)&Hw[(size_t)(bcol + cc) * 256 + kt * 64 + q * 4];
        }
        __syncthreads();
        for (int kk = 0; kk < 64; kk += 4) {
            float4 fv4[4], wv4[4];
            #pragma unroll
            for (int i = 0; i < 4; ++i)
                fv4[i] = *(const float4*)&featL[(ty + 8 * i) * 256 + kt * 64 + kk];
            #pragma unroll
            for (int j = 0; j < 4; ++j)
                wv4[j] = *(const float4*)&HwL[(tx + 32 * j) * 68 + kk];
            #pragma unroll
            for (int i = 0; i < 4; ++i)
                #pragma unroll
                for (int j = 0; j < 4; ++j) {
                    acc[i][j] += fv4[i].x * wv4[j].x;
                    acc[i][j] += fv4[i].y * wv4[j].y;
                    acc[i][j] += fv4[i].z * wv4[j].z;
                    acc[i][j] += fv4[i].w * wv4[j].w;
                }
        }
    }
    #pragma unroll
    for (int i = 0; i < 4; ++i) {
        int r = ty + 8 * i;
        #pragma unroll
        for (int j = 0; j < 4; ++j) {
            int c = bcol + tx + 32 * j;
            float x = acc[i][j] + Hb[c];
            float g = 1.f / (1.f + __expf(-x));
            float fo = ws[OFF_FOUT + (size_t)(brow + r) * 256 + c];
            float e = fo > 0.f ? fo : expm1f(fo);
            float fs = featL[r * 256 + c];
            out[(size_t)(brow + r) * 256 + c] = g * e + (1.f - g) * fs;
        }
    }
}

extern "C" void kernel_launch(void* const* d_in, const int* in_sizes, int n_in,
                              void* d_out, int out_size, void* d_ws, size_t ws_size,
                              hipStream_t stream) {
    const float* feat_src = (const float*)d_in[0];
    const float* feat_dst = (const float*)d_in[1];
    const float* W        = (const float*)d_in[2];
    const float* bias     = (const float*)d_in[3];
    const float* w_src    = (const float*)d_in[4];
    const float* w_dst    = (const float*)d_in[5];
    const float* Hw       = (const float*)d_in[6];
    const float* Hb       = (const float*)d_in[7];
    float* out = (float*)d_out;
    float* ws  = (float*)d_ws;

    k0_wf<<<32, 256, 0, stream>>>(W, ws);
    k1_mfma<<<256, 256, 0, stream>>>(feat_src, feat_dst, w_src, w_dst, ws);
    k2a_sort<<<16, 1024, 0, stream>>>(ws);
    k2b_gather<<<256, 256, 0, stream>>>(ws);
    k2c_scan<<<16, 128, 0, stream>>>(ws);
    k3_out<<<8192, 256, 0, stream>>>(bias, ws);
    k4_gate<<<512, 256, 0, stream>>>(feat_src, Hw, Hb, ws, out);
}

// Round 4
// 117.131 us; speedup vs baseline: 2.7030x; 1.1280x over previous
//
#include <hip/hip_runtime.h>
#include <math.h>

typedef unsigned int uint32;
typedef __attribute__((ext_vector_type(8))) short bf16x8;
typedef __attribute__((ext_vector_type(4))) float f32x4;

#define BB 4
#define HH 4
#define NSRC 2048
#define NDST 2048
#define IND 256
#define OUTD 64
#define ALPHA 0.2f
#define NB 2048           // value buckets per (b,h)
#define NCH 128           // 16-element chunks per (b,h)

// workspace layout (float offsets)
#define OFF_HDST   0            // 2097152
#define OFF_FOUT   2097152      // 2097152
#define OFF_ASRC   4194304      // 32768
#define OFF_ADST   4227072      // 32768
#define OFF_SORTD  4259840      // 32768 (bucket-permuted d)
#define OFF_IDX    4292608      // 32768 (int: orig index at permuted pos)
#define OFF_W1S    4325376      // 32768
#define OFF_W2S    4358144      // 32768
#define OFF_C1     4390912      // 131072
#define OFF_C2     4521984      // 131072
#define OFF_CZ1    4653056      // 2048
#define OFF_CZ2    4655104      // 2048
#define OFF_T1     4657152      // 1024
#define OFF_T2     4658176      // 1024
#define OFF_TZ1    4659200      // 16
#define OFF_TZ2    4659216      // 16
#define OFF_BST    4659232      // 16*2049 ints
#define OFF_MM     4692016      // 16*2 (lo, inv)
#define OFF_WFH    4692048      // 32768 (W frags hi, 65536 bf16)
#define OFF_WFL    4724816      // 32768
#define OFF_GFH    4757584      // 32768 (Hw^T frags hi)
#define OFF_GFL    4790352      // 32768

__device__ __forceinline__ float fast_tanh(float x) {
    float e = __expf(2.f * x);
    return 1.f - 2.f / (e + 1.f);
}

__device__ __forceinline__ uint32 f32_to_bf16_rne(float x) {
    uint32 u = __float_as_uint(x);
    return (u + 0x7fffu + ((u >> 16) & 1u)) >> 16;
}

// stage 64x256 f32 tile -> bf16 hi/lo LDS, XOR-swizzled (byte ^= (row&7)<<4)
__device__ __forceinline__ void stage_bf16_tile(const float4* __restrict__ fb,
                                                unsigned short* Ahi, unsigned short* Alo,
                                                int tid) {
    #pragma unroll
    for (int it = 0; it < 16; ++it) {
        int f4 = it * 256 + tid;
        int row = f4 >> 6, c4 = f4 & 63;
        float4 v = fb[f4];
        float xs[4] = {v.x, v.y, v.z, v.w};
        uint32 hb[4], lb[4];
        #pragma unroll
        for (int j = 0; j < 4; ++j) {
            hb[j] = f32_to_bf16_rne(xs[j]);
            float hf = __uint_as_float(hb[j] << 16);
            lb[j] = f32_to_bf16_rne(xs[j] - hf);
        }
        uint2 hw, lw;
        hw.x = hb[0] | (hb[1] << 16); hw.y = hb[2] | (hb[3] << 16);
        lw.x = lb[0] | (lb[1] << 16); lw.y = lb[2] | (lb[3] << 16);
        int baddr = (row * 512 + c4 * 8) ^ ((row & 7) << 4);
        *(uint2*)((char*)Ahi + baddr) = hw;
        *(uint2*)((char*)Alo + baddr) = lw;
    }
}

// 64x64 out per wave, K=256, split-bf16 3-pass. bfh/bfl: packed B frags.
__device__ __forceinline__ void mfma_64x64(const unsigned short* Ahi, const unsigned short* Alo,
                                           const uint4* __restrict__ bfh,
                                           const uint4* __restrict__ bfl,
                                           int w, int l, f32x4 acc[4][4]) {
    int lr = l & 15, lq = l >> 4;
    for (int ks = 0; ks < 8; ++ks) {
        bf16x8 ah[4], al[4], bh[4], bl[4];
        #pragma unroll
        for (int mi = 0; mi < 4; ++mi) {
            int row = mi * 16 + lr;
            int baddr = (row * 512 + ks * 64 + lq * 16) ^ ((row & 7) << 4);
            ah[mi] = *(const bf16x8*)((const char*)Ahi + baddr);
            al[mi] = *(const bf16x8*)((const char*)Alo + baddr);
        }
        #pragma unroll
        for (int ni = 0; ni < 4; ++ni) {
            int idx = ((w * 8 + ks) * 4 + ni) * 64 + l;
            uint4 th_ = bfh[idx], tl_ = bfl[idx];
            bh[ni] = *(const bf16x8*)&th_;
            bl[ni] = *(const bf16x8*)&tl_;
        }
        #pragma unroll
        for (int mi = 0; mi < 4; ++mi)
            #pragma unroll
            for (int ni = 0; ni < 4; ++ni) {
                acc[mi][ni] = __builtin_amdgcn_mfma_f32_16x16x32_bf16(ah[mi], bh[ni], acc[mi][ni], 0, 0, 0);
                acc[mi][ni] = __builtin_amdgcn_mfma_f32_16x16x32_bf16(ah[mi], bl[ni], acc[mi][ni], 0, 0, 0);
                acc[mi][ni] = __builtin_amdgcn_mfma_f32_16x16x32_bf16(al[mi], bh[ni], acc[mi][ni], 0, 0, 0);
            }
    }
}

// K0: pack W (per-head) and Hw^T into MFMA B-frag order, split bf16 hi/lo.
// B frag: lane l holds B[k = ks*32 + (l>>4)*8 + j][col = ni*16 + (l&15)].
// grid: 64 blocks, 256 threads. slots: [0,8192) W, [8192,16384) Hw.
__global__ __launch_bounds__(256) void k0_pack(const float* __restrict__ W,
                                               const float* __restrict__ Hw,
                                               float* __restrict__ ws) {
    int g = blockIdx.x * 256 + threadIdx.x;
    int which = g >> 13;
    int gg = g & 8191;
    int l = gg & 63, ni = (gg >> 6) & 3, ks = (gg >> 8) & 7, cb = gg >> 11;
    int col = ni * 16 + (l & 15);
    int k0 = ks * 32 + (l >> 4) * 8;
    unsigned short hs[8], lsv[8];
    #pragma unroll
    for (int j = 0; j < 8; ++j) {
        float w = which ? Hw[(size_t)(cb * 64 + col) * 256 + k0 + j]
                        : W[cb * 16384 + (k0 + j) * 64 + col];
        uint32 hb = f32_to_bf16_rne(w);
        float hf = __uint_as_float(hb << 16);
        uint32 lb = f32_to_bf16_rne(w - hf);
        hs[j] = (unsigned short)hb; lsv[j] = (unsigned short)lb;
    }
    unsigned short* fh = (unsigned short*)(ws + (which ? OFF_GFH : OFF_WFH));
    unsigned short* fl = (unsigned short*)(ws + (which ? OFF_GFL : OFF_WFL));
    int slab = ((cb * 8 + ks) * 4 + ni) * 512 + l * 8;
    #pragma unroll
    for (int j = 0; j < 8; ++j) { fh[slab + j] = hs[j]; fl[slab + j] = lsv[j]; }
}

// K1: projection via MFMA. Block: 64 rows x 4 heads (wave w = head w).
// grid: s(2)*b(4)*t(32) = 256 blocks, 256 threads.
__global__ __launch_bounds__(256) void k1_mfma(const float* __restrict__ feat_src,
                                               const float* __restrict__ feat_dst,
                                               const float* __restrict__ w_src,
                                               const float* __restrict__ w_dst,
                                               float* __restrict__ ws) {
    __shared__ __align__(16) unsigned short Ahi[64 * 256];
    __shared__ __align__(16) unsigned short Alo[64 * 256];
    int bid = blockIdx.x;
    int t = bid & 31, b = (bid >> 5) & 3, s = bid >> 7;
    int tid = threadIdx.x;
    const float* feat = s ? feat_dst : feat_src;
    const float4* fb = (const float4*)(feat + ((size_t)b * 2048 + t * 64) * IND);
    stage_bf16_tile(fb, Ahi, Alo, tid);
    __syncthreads();
    int w = tid >> 6, l = tid & 63;
    int lr = l & 15, lq = l >> 4;
    f32x4 acc[4][4];
    #pragma unroll
    for (int mi = 0; mi < 4; ++mi)
        #pragma unroll
        for (int ni = 0; ni < 4; ++ni) acc[mi][ni] = (f32x4)0.f;
    mfma_64x64(Ahi, Alo, (const uint4*)(ws + OFF_WFH), (const uint4*)(ws + OFF_WFL), w, l, acc);
    if (s) {
        float* hd = ws + OFF_HDST + ((size_t)(b * HH + w) * NDST + t * 64) * OUTD;
        #pragma unroll
        for (int mi = 0; mi < 4; ++mi)
            #pragma unroll
            for (int ni = 0; ni < 4; ++ni)
                #pragma unroll
                for (int r = 0; r < 4; ++r)
                    hd[(mi * 16 + lq * 4 + r) * 64 + ni * 16 + lr] = acc[mi][ni][r];
    }
    const float* wa = (s ? w_dst : w_src) + w * OUTD;
    float wa_v[4];
    #pragma unroll
    for (int ni = 0; ni < 4; ++ni) wa_v[ni] = wa[ni * 16 + lr];
    float* ap = ws + (s ? OFF_ADST : OFF_ASRC) + (b * HH + w) * NSRC + t * 64;
    #pragma unroll
    for (int mi = 0; mi < 4; ++mi)
        #pragma unroll
        for (int r = 0; r < 4; ++r) {
            float p = 0.f;
            #pragma unroll
            for (int ni = 0; ni < 4; ++ni) p += fast_tanh(acc[mi][ni][r]) * wa_v[ni];
            p += __shfl_xor(p, 1); p += __shfl_xor(p, 2);
            p += __shfl_xor(p, 4); p += __shfl_xor(p, 8);
            if (lr == 0) ap[mi * 16 + lq * 4 + r] = p;
        }
}

// KH: per (b,h): min/max -> 2048-bucket histogram -> block scan -> scatter
// (exact bucket permutation replacing the bitonic sort). grid: 16 x 1024.
__global__ __launch_bounds__(1024) void kh_bucket(float* __restrict__ ws) {
    __shared__ int hist[NB];
    __shared__ int cnt[NB];
    __shared__ float red[32];
    __shared__ float loinv[2];
    __shared__ int wtot[16];
    int bh = blockIdx.x, tid = threadIdx.x;
    int lane = tid & 63, wv = tid >> 6;
    const float* ad = ws + OFF_ADST + bh * NDST;
    float d0 = ad[tid], d1 = ad[tid + 1024];
    float mn = fminf(d0, d1), mx = fmaxf(d0, d1);
    #pragma unroll
    for (int off = 32; off; off >>= 1) {
        mn = fminf(mn, __shfl_xor(mn, off));
        mx = fmaxf(mx, __shfl_xor(mx, off));
    }
    if (lane == 0) { red[wv] = mn; red[16 + wv] = mx; }
    hist[tid] = 0; hist[tid + 1024] = 0;
    __syncthreads();
    if (tid == 0) {
        float lo = red[0], hi = red[16];
        #pragma unroll
        for (int i = 1; i < 16; ++i) { lo = fminf(lo, red[i]); hi = fmaxf(hi, red[16 + i]); }
        float wd = hi - lo;
        float inv = (float)NB / (wd + wd * 1e-6f + 1e-30f);
        loinv[0] = lo; loinv[1] = inv;
        ws[OFF_MM + bh * 2] = lo; ws[OFF_MM + bh * 2 + 1] = inv;
    }
    __syncthreads();
    float lo = loinv[0], inv = loinv[1];
    int b0 = (int)((d0 - lo) * inv); b0 = b0 < 0 ? 0 : (b0 > NB - 1 ? NB - 1 : b0);
    int b1 = (int)((d1 - lo) * inv); b1 = b1 < 0 ? 0 : (b1 > NB - 1 ? NB - 1 : b1);
    atomicAdd(&hist[b0], 1);
    atomicAdd(&hist[b1], 1);
    __syncthreads();
    // exclusive scan over 2048 buckets; thread t owns buckets 2t, 2t+1
    int h0 = hist[2 * tid], h1 = hist[2 * tid + 1];
    int s = h0 + h1, sc = s;
    #pragma unroll
    for (int off = 1; off < 64; off <<= 1) {
        int v = __shfl_up(sc, off);
        if (lane >= off) sc += v;
    }
    if (lane == 63) wtot[wv] = sc;
    __syncthreads();
    if (tid == 0) {
        int r = 0;
        #pragma unroll
        for (int i = 0; i < 16; ++i) { int v = wtot[i]; wtot[i] = r; r += v; }
    }
    __syncthreads();
    int base = wtot[wv] + (sc - s);
    int* bstg = (int*)(ws + OFF_BST) + bh * (NB + 1);
    cnt[2 * tid] = base;       bstg[2 * tid] = base;
    cnt[2 * tid + 1] = base + h0; bstg[2 * tid + 1] = base + h0;
    if (tid == 0) bstg[NB] = NDST;
    __syncthreads();
    int* idxg = (int*)(ws + OFF_IDX) + bh * NDST;
    float* sdg = ws + OFF_SORTD + bh * NDST;
    float* w1g = ws + OFF_W1S + bh * NDST;
    float* w2g = ws + OFF_W2S + bh * NDST;
    int p0 = atomicAdd(&cnt[b0], 1);
    sdg[p0] = d0; idxg[p0] = tid;
    w1g[p0] = expf(d0); w2g[p0] = expf(ALPHA * d0);
    int p1 = atomicAdd(&cnt[b1], 1);
    sdg[p1] = d1; idxg[p1] = tid + 1024;
    w1g[p1] = expf(d1); w2g[p1] = expf(ALPHA * d1);
}

// K2b: chunk-16 partial sums in permuted order (no V materialization).
// grid: 512 blocks, 256 threads (1 wave = 1 chunk).
__global__ __launch_bounds__(256) void k2b_sums(float* __restrict__ ws) {
    int gw = blockIdx.x * 4 + (threadIdx.x >> 6);   // 0..2047
    int o = threadIdx.x & 63;
    int bh = gw >> 7, chunk = gw & 127;
    const int* idxp = (const int*)(ws + OFF_IDX) + bh * NDST;
    const float* w1s = ws + OFF_W1S + bh * NDST;
    const float* w2s = ws + OFF_W2S + bh * NDST;
    const float* hd = ws + OFF_HDST + (size_t)bh * NDST * OUTD;
    float c1 = 0.f, c2 = 0.f, cz1 = 0.f, cz2 = 0.f;
    #pragma unroll 4
    for (int ii = 0; ii < 16; ++ii) {
        int i = chunk * 16 + ii;
        int m = idxp[i];
        float w1 = w1s[i], w2 = w2s[i];
        float hv = hd[m * 64 + o];
        c1 += w1 * hv; c2 += w2 * hv; cz1 += w1; cz2 += w2;
    }
    ws[OFF_C1 + (bh * NCH + chunk) * 64 + o] = c1;
    ws[OFF_C2 + (bh * NCH + chunk) * 64 + o] = c2;
    if (o == 0) {
        ws[OFF_CZ1 + bh * NCH + chunk] = cz1;
        ws[OFF_CZ2 + bh * NCH + chunk] = cz2;
    }
}

// K2c: exclusive scan of chunk totals. grid: 16 blocks, 128 threads.
__global__ __launch_bounds__(128) void k2c_scan(float* __restrict__ ws) {
    int bh = blockIdx.x;
    int tid = threadIdx.x;
    int o = tid & 63, w = tid >> 6;
    float* C = ws + (w == 0 ? OFF_C1 : OFF_C2) + bh * NCH * 64;
    float run = 0.f;
    for (int c = 0; c < NCH; ++c) {
        float v = C[c * 64 + o];
        C[c * 64 + o] = run;
        run += v;
    }
    ws[(w == 0 ? OFF_T1 : OFF_T2) + bh * 64 + o] = run;
    if (o == 0) {
        float* CZ = ws + (w == 0 ? OFF_CZ1 : OFF_CZ2) + bh * NCH;
        float rz = 0.f;
        for (int c = 0; c < NCH; ++c) {
            float v = CZ[c];
            CZ[c] = rz;
            rz += v;
        }
        ws[(w == 0 ? OFF_TZ1 : OFF_TZ2) + bh] = rz;
    }
}

// K3: per (b,h,n): bucket lookup + coarse prefix + branchless remainder.
// grid: 8192 blocks, 256 threads (one wave per query row, lane=o).
__global__ __launch_bounds__(256) void k3_out(const float* __restrict__ bias,
                                              float* __restrict__ ws) {
    int tid = threadIdx.x;
    int wid = blockIdx.x * 4 + (tid >> 6);
    int o = tid & 63;
    int n = wid & 2047;
    int bh = wid >> 11;
    float t = ws[OFF_ASRC + bh * 2048 + n];
    float th = -t;
    float lo = ws[OFF_MM + bh * 2], inv = ws[OFF_MM + bh * 2 + 1];
    int b = (int)floorf((th - lo) * inv);
    b = b < 0 ? 0 : (b > NB - 1 ? NB - 1 : b);
    const int* bstg = (const int*)(ws + OFF_BST) + bh * (NB + 1);
    int jstart = bstg[b], jend = bstg[b + 1];
    int c = jstart >> 4; if (c > NCH - 1) c = NCH - 1;
    int i0 = c << 4;
    float p1 = ws[OFF_C1 + (bh * NCH + c) * 64 + o];
    float p2 = ws[OFF_C2 + (bh * NCH + c) * 64 + o];
    float zp1 = ws[OFF_CZ1 + bh * NCH + c];
    float zp2 = ws[OFF_CZ2 + bh * NCH + c];
    const float* sd = ws + OFF_SORTD + bh * 2048;
    const float* w1s = ws + OFF_W1S + bh * 2048;
    const float* w2s = ws + OFF_W2S + bh * 2048;
    const int* idxp = (const int*)(ws + OFF_IDX) + bh * 2048;
    const float* hd = ws + OFF_HDST + (size_t)bh * NDST * OUTD;
    for (int i = i0; i < jend; ++i) {
        float d = sd[i];
        float sel = d <= th ? 1.f : 0.f;
        int m = idxp[i];
        float hv = hd[m * 64 + o];
        float w1 = w1s[i] * sel, w2 = w2s[i] * sel;
        p1 += w1 * hv; p2 += w2 * hv; zp1 += w1; zp2 += w2;
    }
    float T1v = ws[OFF_T1 + bh * 64 + o];
    float tz1 = ws[OFF_TZ1 + bh], tz2 = ws[OFF_TZ2 + bh];
    float et = __expf(t), et2 = __expf(ALPHA * t);
    float num = et * (T1v - p1) + et2 * p2;
    float den = et * (tz1 - zp1) + et2 * zp2;
    float val = num / den + bias[o];
    ws[OFF_FOUT + ((size_t)(bh >> 2) * NSRC + n) * 256 + (bh & 3) * 64 + o] = val;
}

// K4: gate GEMM via MFMA + fused epilogue. Block: 64 rows x 256 cols, 4 waves.
// grid: 128 blocks, 256 threads.
__global__ __launch_bounds__(256) void k4_mfma(const float* __restrict__ feat_src,
                                               const float* __restrict__ Hb,
                                               const float* __restrict__ ws,
                                               float* __restrict__ out) {
    __shared__ __align__(16) unsigned short Ahi[64 * 256];
    __shared__ __align__(16) unsigned short Alo[64 * 256];
    int bid = blockIdx.x;
    int tid = threadIdx.x;
    int brow = bid * 64;
    const float4* fb = (const float4*)(feat_src + (size_t)brow * 256);
    stage_bf16_tile(fb, Ahi, Alo, tid);
    __syncthreads();
    int w = tid >> 6, l = tid & 63;
    int lr = l & 15, lq = l >> 4;
    f32x4 acc[4][4];
    #pragma unroll
    for (int mi = 0; mi < 4; ++mi)
        #pragma unroll
        for (int ni = 0; ni < 4; ++ni) acc[mi][ni] = (f32x4)0.f;
    mfma_64x64(Ahi, Alo, (const uint4*)(ws + OFF_GFH), (const uint4*)(ws + OFF_GFL), w, l, acc);
    const float* FOUT = ws + OFF_FOUT;
    #pragma unroll
    for (int mi = 0; mi < 4; ++mi)
        #pragma unroll
        for (int ni = 0; ni < 4; ++ni) {
            int c = w * 64 + ni * 16 + lr;
            float hbv = Hb[c];
            #pragma unroll
            for (int r = 0; r < 4; ++r) {
                size_t rg = brow + mi * 16 + lq * 4 + r;
                float x = acc[mi][ni][r] + hbv;
                float g = 1.f / (1.f + __expf(-x));
                float fo = FOUT[rg * 256 + c];
                float e = fo > 0.f ? fo : expm1f(fo);
                float fs = feat_src[rg * 256 + c];
                out[rg * 256 + c] = g * e + (1.f - g) * fs;
            }
        }
}

extern "C" void kernel_launch(void* const* d_in, const int* in_sizes, int n_in,
                              void* d_out, int out_size, void* d_ws, size_t ws_size,
                              hipStream_t stream) {
    const float* feat_src = (const float*)d_in[0];
    const float* feat_dst = (const float*)d_in[1];
    const float* W        = (const float*)d_in[2];
    const float* bias     = (const float*)d_in[3];
    const float* w_src    = (const float*)d_in[4];
    const float* w_dst    = (const float*)d_in[5];
    const float* Hw       = (const float*)d_in[6];
    const float* Hb       = (const float*)d_in[7];
    float* out = (float*)d_out;
    float* ws  = (float*)d_ws;

    k0_pack<<<64, 256, 0, stream>>>(W, Hw, ws);
    k1_mfma<<<256, 256, 0, stream>>>(feat_src, feat_dst, w_src, w_dst, ws);
    kh_bucket<<<16, 1024, 0, stream>>>(ws);
    k2b_sums<<<512, 256, 0, stream>>>(ws);
    k2c_scan<<<16, 128, 0, stream>>>(ws);
    k3_out<<<8192, 256, 0, stream>>>(bias, ws);
    k4_mfma<<<128, 256, 0, stream>>>(feat_src, Hb, ws, out);
}

// Round 5
// 103.901 us; speedup vs baseline: 3.0472x; 1.1273x over previous
//
#include <hip/hip_runtime.h>
#include <math.h>

typedef unsigned int uint32;
typedef __attribute__((ext_vector_type(8))) short bf16x8;
typedef __attribute__((ext_vector_type(4))) float f32x4;

#define BB 4
#define HH 4
#define NSRC 2048
#define NDST 2048
#define IND 256
#define OUTD 64
#define ALPHA 0.2f
#define NB 2048           // value buckets per (b,h)
#define NCH 128           // 16-element chunks per (b,h)

// workspace layout (float offsets)
#define OFF_HDST   0            // 2097152
#define OFF_ASRC   2097152      // 32768
#define OFF_ADST   2129920      // 32768
#define OFF_SORTD  2162688      // 32768 (bucket-permuted d)
#define OFF_IDX    2195456      // 32768 (int)
#define OFF_W1S    2228224      // 32768
#define OFF_W2S    2260992      // 32768
#define OFF_C1     2293760      // 131072 (chunk prefix, exclusive)
#define OFF_C2     2424832      // 131072
#define OFF_CZ1    2555904      // 2048
#define OFF_CZ2    2557952      // 2048
#define OFF_T1     2560000      // 1024
#define OFF_TZ1    2561024      // 16
#define OFF_TZ2    2561040      // 16
#define OFF_BST    2561056      // 16*2049 ints
#define OFF_MM     2593840      // 16*2 (lo, inv)

__device__ __forceinline__ float fast_tanh(float x) {
    float e = __expf(2.f * x);
    return 1.f - 2.f / (e + 1.f);
}

__device__ __forceinline__ uint32 f32_to_bf16_rne(float x) {
    uint32 u = __float_as_uint(x);
    return (u + 0x7fffu + ((u >> 16) & 1u)) >> 16;
}

// split 8 f32 into bf16 hi/lo packed fragments
__device__ __forceinline__ void split8(const float* x, bf16x8& h8, bf16x8& l8) {
    uint32 hw[4], lw[4];
    #pragma unroll
    for (int p = 0; p < 4; ++p) {
        uint32 h0 = f32_to_bf16_rne(x[2 * p]);
        float f0 = __uint_as_float(h0 << 16);
        uint32 l0 = f32_to_bf16_rne(x[2 * p] - f0);
        uint32 h1 = f32_to_bf16_rne(x[2 * p + 1]);
        float f1 = __uint_as_float(h1 << 16);
        uint32 l1 = f32_to_bf16_rne(x[2 * p + 1] - f1);
        hw[p] = h0 | (h1 << 16);
        lw[p] = l0 | (l1 << 16);
    }
    h8 = *(bf16x8*)hw; l8 = *(bf16x8*)lw;
}

// K1: projection via MFMA, split-bf16 3-pass. Block: 64 rows x 4 heads
// (wave w = head w). W fragments gathered per-lane from global (L2-resident).
// grid: s(2)*b(4)*t(32) = 256 blocks, 256 threads.
__global__ __launch_bounds__(256) void k1_mfma(const float* __restrict__ feat_src,
                                               const float* __restrict__ feat_dst,
                                               const float* __restrict__ W,
                                               const float* __restrict__ w_src,
                                               const float* __restrict__ w_dst,
                                               float* __restrict__ ws) {
    __shared__ __align__(16) unsigned short Ahi[64 * 256];
    __shared__ __align__(16) unsigned short Alo[64 * 256];
    int bid = blockIdx.x;
    int t = bid & 31, b = (bid >> 5) & 3, s = bid >> 7;
    int tid = threadIdx.x;
    const float* feat = s ? feat_dst : feat_src;
    const float4* fb = (const float4*)(feat + ((size_t)b * 2048 + t * 64) * IND);
    // stage feat tile -> bf16 hi/lo LDS, XOR swizzle (byte ^= (row&7)<<4)
    #pragma unroll
    for (int it = 0; it < 16; ++it) {
        int f4 = it * 256 + tid;
        int row = f4 >> 6, c4 = f4 & 63;
        float4 v = fb[f4];
        float xs[4] = {v.x, v.y, v.z, v.w};
        uint32 hb[4], lb[4];
        #pragma unroll
        for (int j = 0; j < 4; ++j) {
            hb[j] = f32_to_bf16_rne(xs[j]);
            float hf = __uint_as_float(hb[j] << 16);
            lb[j] = f32_to_bf16_rne(xs[j] - hf);
        }
        uint2 hw, lw;
        hw.x = hb[0] | (hb[1] << 16); hw.y = hb[2] | (hb[3] << 16);
        lw.x = lb[0] | (lb[1] << 16); lw.y = lb[2] | (lb[3] << 16);
        int baddr = (row * 512 + c4 * 8) ^ ((row & 7) << 4);
        *(uint2*)((char*)Ahi + baddr) = hw;
        *(uint2*)((char*)Alo + baddr) = lw;
    }
    __syncthreads();
    int w = tid >> 6, l = tid & 63;
    int lr = l & 15, lq = l >> 4;
    const float* Wh = W + (size_t)w * 16384;
    f32x4 acc[4][4];
    #pragma unroll
    for (int mi = 0; mi < 4; ++mi)
        #pragma unroll
        for (int ni = 0; ni < 4; ++ni) acc[mi][ni] = (f32x4)0.f;
    for (int ks = 0; ks < 8; ++ks) {
        bf16x8 ah[4], al[4], bh8[4], bl8[4];
        #pragma unroll
        for (int mi = 0; mi < 4; ++mi) {
            int row = mi * 16 + lr;
            int baddr = (row * 512 + ks * 64 + lq * 16) ^ ((row & 7) << 4);
            ah[mi] = *(const bf16x8*)((const char*)Ahi + baddr);
            al[mi] = *(const bf16x8*)((const char*)Alo + baddr);
        }
        int kb = ks * 32 + lq * 8;
        #pragma unroll
        for (int ni = 0; ni < 4; ++ni) {
            const float* wp = Wh + (size_t)kb * 64 + ni * 16 + lr;
            float xv[8];
            #pragma unroll
            for (int j = 0; j < 8; ++j) xv[j] = wp[j * 64];
            split8(xv, bh8[ni], bl8[ni]);
        }
        #pragma unroll
        for (int mi = 0; mi < 4; ++mi)
            #pragma unroll
            for (int ni = 0; ni < 4; ++ni) {
                acc[mi][ni] = __builtin_amdgcn_mfma_f32_16x16x32_bf16(ah[mi], bh8[ni], acc[mi][ni], 0, 0, 0);
                acc[mi][ni] = __builtin_amdgcn_mfma_f32_16x16x32_bf16(ah[mi], bl8[ni], acc[mi][ni], 0, 0, 0);
                acc[mi][ni] = __builtin_amdgcn_mfma_f32_16x16x32_bf16(al[mi], bh8[ni], acc[mi][ni], 0, 0, 0);
            }
    }
    if (s) {
        float* hd = ws + OFF_HDST + ((size_t)(b * HH + w) * NDST + t * 64) * OUTD;
        #pragma unroll
        for (int mi = 0; mi < 4; ++mi)
            #pragma unroll
            for (int ni = 0; ni < 4; ++ni)
                #pragma unroll
                for (int r = 0; r < 4; ++r)
                    hd[(mi * 16 + lq * 4 + r) * 64 + ni * 16 + lr] = acc[mi][ni][r];
    }
    const float* wa = (s ? w_dst : w_src) + w * OUTD;
    float wa_v[4];
    #pragma unroll
    for (int ni = 0; ni < 4; ++ni) wa_v[ni] = wa[ni * 16 + lr];
    float* ap = ws + (s ? OFF_ADST : OFF_ASRC) + (b * HH + w) * NSRC + t * 64;
    #pragma unroll
    for (int mi = 0; mi < 4; ++mi)
        #pragma unroll
        for (int r = 0; r < 4; ++r) {
            float p = 0.f;
            #pragma unroll
            for (int ni = 0; ni < 4; ++ni) p += fast_tanh(acc[mi][ni][r]) * wa_v[ni];
            p += __shfl_xor(p, 1); p += __shfl_xor(p, 2);
            p += __shfl_xor(p, 4); p += __shfl_xor(p, 8);
            if (lr == 0) ap[mi * 16 + lq * 4 + r] = p;
        }
}

// KMID: per (b,h) in ONE block: bucket permutation (LDS-resident) +
// chunk-16 sums (gather h_dst) + chunk-prefix scan + write all structures.
// grid: 16 blocks, 1024 threads.
__global__ __launch_bounds__(1024) void kmid(float* __restrict__ ws) {
    __shared__ float keys[2048];      // 8KB
    __shared__ int   hist[2048];      // 8KB (counts -> reused as scatter cursors)
    __shared__ float keysP[2048];     // 8KB permuted
    __shared__ int   idxP[2048];      // 8KB
    __shared__ float w1L[2048];       // 8KB
    __shared__ float w2L[2048];       // 8KB
    __shared__ float CZ1L[128], CZ2L[128];
    __shared__ float ST1[16 * 64], ST2[16 * 64];   // strip totals [s][o]
    __shared__ float SZ1[16], SZ2[16];
    __shared__ float red[32];
    __shared__ float loinv[2];
    __shared__ int wtot[16];
    int bh = blockIdx.x, tid = threadIdx.x;
    int lane = tid & 63, wv = tid >> 6;
    const float* ad = ws + OFF_ADST + bh * NDST;
    float d0 = ad[tid], d1 = ad[tid + 1024];
    keys[tid] = d0; keys[tid + 1024] = d1;
    float mn = fminf(d0, d1), mx = fmaxf(d0, d1);
    #pragma unroll
    for (int off = 32; off; off >>= 1) {
        mn = fminf(mn, __shfl_xor(mn, off));
        mx = fmaxf(mx, __shfl_xor(mx, off));
    }
    if (lane == 0) { red[wv] = mn; red[16 + wv] = mx; }
    hist[tid] = 0; hist[tid + 1024] = 0;
    __syncthreads();
    if (tid == 0) {
        float lo = red[0], hi = red[16];
        #pragma unroll
        for (int i = 1; i < 16; ++i) { lo = fminf(lo, red[i]); hi = fmaxf(hi, red[16 + i]); }
        float wd = hi - lo;
        float inv = (float)NB / (wd + wd * 1e-6f + 1e-30f);
        loinv[0] = lo; loinv[1] = inv;
        ws[OFF_MM + bh * 2] = lo; ws[OFF_MM + bh * 2 + 1] = inv;
    }
    __syncthreads();
    float lo = loinv[0], inv = loinv[1];
    int b0 = (int)((d0 - lo) * inv); b0 = b0 < 0 ? 0 : (b0 > NB - 1 ? NB - 1 : b0);
    int b1 = (int)((d1 - lo) * inv); b1 = b1 < 0 ? 0 : (b1 > NB - 1 ? NB - 1 : b1);
    atomicAdd(&hist[b0], 1);
    atomicAdd(&hist[b1], 1);
    __syncthreads();
    int h0 = hist[2 * tid], h1 = hist[2 * tid + 1];
    int s = h0 + h1, sc = s;
    #pragma unroll
    for (int off = 1; off < 64; off <<= 1) {
        int v = __shfl_up(sc, off);
        if (lane >= off) sc += v;
    }
    if (lane == 63) wtot[wv] = sc;
    __syncthreads();
    if (tid == 0) {
        int r = 0;
        #pragma unroll
        for (int i = 0; i < 16; ++i) { int v = wtot[i]; wtot[i] = r; r += v; }
    }
    __syncthreads();
    int base = wtot[wv] + (sc - s);
    int* bstg = (int*)(ws + OFF_BST) + bh * (NB + 1);
    hist[2 * tid] = base;          // reuse hist as scatter cursor
    hist[2 * tid + 1] = base + h0;
    bstg[2 * tid] = base;
    bstg[2 * tid + 1] = base + h0;
    if (tid == 0) bstg[NB] = NDST;
    __syncthreads();
    int p0 = atomicAdd(&hist[b0], 1);
    keysP[p0] = d0; idxP[p0] = tid;
    w1L[p0] = __expf(d0); w2L[p0] = __expf(ALPHA * d0);
    int p1 = atomicAdd(&hist[b1], 1);
    keysP[p1] = d1; idxP[p1] = tid + 1024;
    w1L[p1] = __expf(d1); w2L[p1] = __expf(ALPHA * d1);
    __syncthreads();
    // dump permuted arrays to global (k34 remainder reads them)
    {
        float* sdg = ws + OFF_SORTD + bh * NDST;
        int* idxg = (int*)(ws + OFF_IDX) + bh * NDST;
        float* w1g = ws + OFF_W1S + bh * NDST;
        float* w2g = ws + OFF_W2S + bh * NDST;
        sdg[tid] = keysP[tid];        sdg[tid + 1024] = keysP[tid + 1024];
        idxg[tid] = idxP[tid];        idxg[tid + 1024] = idxP[tid + 1024];
        w1g[tid] = w1L[tid];          w1g[tid + 1024] = w1L[tid + 1024];
        w2g[tid] = w2L[tid];          w2g[tid + 1024] = w2L[tid + 1024];
    }
    // chunk-16 sums: wave wv owns chunks wv*8..wv*8+8, lane = o
    const float* hd = ws + OFF_HDST + (size_t)bh * NDST * OUTD;
    float* C1g = ws + OFF_C1 + (size_t)bh * NCH * 64;
    float* C2g = ws + OFF_C2 + (size_t)bh * NCH * 64;
    int o = lane;
    float csum1[8], csum2[8];
    #pragma unroll
    for (int k = 0; k < 8; ++k) {
        int c = wv * 8 + k;
        float c1 = 0.f, c2 = 0.f, cz1 = 0.f, cz2 = 0.f;
        #pragma unroll 4
        for (int ii = 0; ii < 16; ++ii) {
            int i = c * 16 + ii;
            int m = idxP[i];
            float w1 = w1L[i], w2 = w2L[i];
            float hv = hd[m * 64 + o];
            c1 += w1 * hv; c2 += w2 * hv; cz1 += w1; cz2 += w2;
        }
        csum1[k] = c1; csum2[k] = c2;
        if (o == 0) { CZ1L[c] = cz1; CZ2L[c] = cz2; }
    }
    // strip scan (wave wv = strip wv), conflict-free [s][o] layout
    float run1 = 0.f, run2 = 0.f;
    float sv1[8], sv2[8];
    #pragma unroll
    for (int q = 0; q < 8; ++q) {
        sv1[q] = run1; sv2[q] = run2;
        run1 += csum1[q]; run2 += csum2[q];
    }
    ST1[wv * 64 + o] = run1; ST2[wv * 64 + o] = run2;
    float rz1 = 0.f, rz2 = 0.f;
    float zv1[8], zv2[8];
    __syncthreads();
    if (lane == 0) {
        #pragma unroll
        for (int q = 0; q < 8; ++q) {
            int c = wv * 8 + q;
            zv1[q] = rz1; zv2[q] = rz2;
            rz1 += CZ1L[c]; rz2 += CZ2L[c];
        }
        SZ1[wv] = rz1; SZ2[wv] = rz2;
    }
    __syncthreads();
    float base1 = 0.f, base2 = 0.f;
    for (int ss = 0; ss < wv; ++ss) { base1 += ST1[ss * 64 + o]; base2 += ST2[ss * 64 + o]; }
    #pragma unroll
    for (int q = 0; q < 8; ++q) {
        int c = wv * 8 + q;
        C1g[c * 64 + o] = base1 + sv1[q];
        C2g[c * 64 + o] = base2 + sv2[q];
    }
    if (wv == 15) ws[OFF_T1 + bh * 64 + o] = base1 + run1;
    if (lane == 0) {
        float zb1 = 0.f, zb2 = 0.f;
        for (int ss = 0; ss < wv; ++ss) { zb1 += SZ1[ss]; zb2 += SZ2[ss]; }
        #pragma unroll
        for (int q = 0; q < 8; ++q) {
            int c = wv * 8 + q;
            ws[OFF_CZ1 + bh * NCH + c] = zb1 + zv1[q];
            ws[OFF_CZ2 + bh * NCH + c] = zb2 + zv2[q];
        }
        if (wv == 15) { ws[OFF_TZ1 + bh] = zb1 + rz1; ws[OFF_TZ2 + bh] = zb2 + rz2; }
    }
}

// K34: fused attention-output + gate. Block: 32 src rows x 256 cols, 8 waves.
// Phase1: each wave computes 16 (h,n)-rows of feat_out into LDS (nearest-chunk
// prefix + signed remainder). Phase2: gate MFMA (Hw gathered contiguous) +
// fused elu/sigmoid/mix epilogue. grid: b(4)*ntile(64) = 256 blocks, 512 thr.
__global__ __launch_bounds__(512) void k34(const float* __restrict__ feat_src,
                                           const float* __restrict__ Hw,
                                           const float* __restrict__ Hb,
                                           const float* __restrict__ bias,
                                           const float* __restrict__ ws,
                                           float* __restrict__ out) {
    __shared__ float FOUT[32 * 256];                 // 32KB
    __shared__ __align__(16) unsigned short Ahi[32 * 256];  // 16KB
    __shared__ __align__(16) unsigned short Alo[32 * 256];  // 16KB
    int bid = blockIdx.x;
    int b = bid >> 6, brow = (bid & 63) * 32;
    int tid = threadIdx.x;
    int o = tid & 63;
    int wv = __builtin_amdgcn_readfirstlane(tid >> 6);
    // phase 0: stage 32 feat rows as bf16 hi/lo
    const float4* fb = (const float4*)(feat_src + ((size_t)b * 2048 + brow) * IND);
    #pragma unroll
    for (int it = 0; it < 4; ++it) {
        int f4 = it * 512 + tid;
        int row = f4 >> 6, c4 = f4 & 63;
        float4 v = fb[f4];
        float xs[4] = {v.x, v.y, v.z, v.w};
        uint32 hb[4], lb[4];
        #pragma unroll
        for (int j = 0; j < 4; ++j) {
            hb[j] = f32_to_bf16_rne(xs[j]);
            float hf = __uint_as_float(hb[j] << 16);
            lb[j] = f32_to_bf16_rne(xs[j] - hf);
        }
        uint2 hw, lw;
        hw.x = hb[0] | (hb[1] << 16); hw.y = hb[2] | (hb[3] << 16);
        lw.x = lb[0] | (lb[1] << 16); lw.y = lb[2] | (lb[3] << 16);
        int baddr = (row * 512 + c4 * 8) ^ ((row & 7) << 4);
        *(uint2*)((char*)Ahi + baddr) = hw;
        *(uint2*)((char*)Alo + baddr) = lw;
    }
    // phase 1: 16 attention-output rows per wave
    float biasv = bias[o];
    for (int r16 = 0; r16 < 16; ++r16) {
        int pair = wv * 16 + r16;
        int h = pair & 3, nn = pair >> 2;
        int bh = b * 4 + h;
        int n = brow + nn;
        float t = ws[OFF_ASRC + bh * 2048 + n];
        float th = -t;
        float blo = ws[OFF_MM + bh * 2], binv = ws[OFF_MM + bh * 2 + 1];
        int bk = (int)floorf((th - blo) * binv);
        bk = bk < 0 ? 0 : (bk > NB - 1 ? NB - 1 : bk);
        const int* bst = (const int*)(ws + OFF_BST) + bh * (NB + 1);
        int jstart = bst[bk], jend = bst[bk + 1];
        int cch = (jstart + 8) >> 4; if (cch > NCH - 1) cch = NCH - 1;
        int i0c = cch << 4;
        int lo2 = i0c < jstart ? i0c : jstart;
        int hi2 = i0c > jend ? i0c : jend;
        float p1 = ws[OFF_C1 + ((size_t)bh * NCH + cch) * 64 + o];
        float p2 = ws[OFF_C2 + ((size_t)bh * NCH + cch) * 64 + o];
        float zp1 = ws[OFF_CZ1 + bh * NCH + cch];
        float zp2 = ws[OFF_CZ2 + bh * NCH + cch];
        const float* sd = ws + OFF_SORTD + bh * 2048;
        const float* w1s = ws + OFF_W1S + bh * 2048;
        const float* w2s = ws + OFF_W2S + bh * 2048;
        const int* idxp = (const int*)(ws + OFF_IDX) + bh * 2048;
        const float* hd = ws + OFF_HDST + (size_t)bh * NDST * OUTD;
        for (int i = lo2; i < hi2; ++i) {
            float d = sd[i];
            int m = idxp[i];
            float sel = (d <= th ? 1.f : 0.f) - (i < i0c ? 1.f : 0.f);
            float w1 = w1s[i] * sel, w2 = w2s[i] * sel;
            float hv = hd[m * 64 + o];
            p1 += w1 * hv; p2 += w2 * hv; zp1 += w1; zp2 += w2;
        }
        float T1v = ws[OFF_T1 + bh * 64 + o];
        float tz1 = ws[OFF_TZ1 + bh], tz2 = ws[OFF_TZ2 + bh];
        float et = __expf(t), et2 = __expf(ALPHA * t);
        float num = et * (T1v - p1) + et2 * p2;
        float den = et * (tz1 - zp1) + et2 * zp2;
        FOUT[nn * 256 + h * 64 + o] = num / den + biasv;
    }
    __syncthreads();
    // phase 2: gate GEMM (wave wv -> cols wv*32..+32), K=256
    int l = tid & 63;
    int lr = l & 15, lq = l >> 4;
    f32x4 acc[2][2];
    #pragma unroll
    for (int mi = 0; mi < 2; ++mi)
        #pragma unroll
        for (int ni = 0; ni < 2; ++ni) acc[mi][ni] = (f32x4)0.f;
    for (int ks = 0; ks < 8; ++ks) {
        bf16x8 ah[2], al[2], bh8[2], bl8[2];
        #pragma unroll
        for (int mi = 0; mi < 2; ++mi) {
            int row = mi * 16 + lr;
            int baddr = (row * 512 + ks * 64 + lq * 16) ^ ((row & 7) << 4);
            ah[mi] = *(const bf16x8*)((const char*)Ahi + baddr);
            al[mi] = *(const bf16x8*)((const char*)Alo + baddr);
        }
        int kb = ks * 32 + lq * 8;
        #pragma unroll
        for (int ni = 0; ni < 2; ++ni) {
            int col = wv * 32 + ni * 16 + lr;
            const float4* hp = (const float4*)(Hw + (size_t)col * 256 + kb);
            float4 va = hp[0], vb = hp[1];
            float xv[8] = {va.x, va.y, va.z, va.w, vb.x, vb.y, vb.z, vb.w};
            split8(xv, bh8[ni], bl8[ni]);
        }
        #pragma unroll
        for (int mi = 0; mi < 2; ++mi)
            #pragma unroll
            for (int ni = 0; ni < 2; ++ni) {
                acc[mi][ni] = __builtin_amdgcn_mfma_f32_16x16x32_bf16(ah[mi], bh8[ni], acc[mi][ni], 0, 0, 0);
                acc[mi][ni] = __builtin_amdgcn_mfma_f32_16x16x32_bf16(ah[mi], bl8[ni], acc[mi][ni], 0, 0, 0);
                acc[mi][ni] = __builtin_amdgcn_mfma_f32_16x16x32_bf16(al[mi], bh8[ni], acc[mi][ni], 0, 0, 0);
            }
    }
    // epilogue: gate + elu + mix
    #pragma unroll
    for (int mi = 0; mi < 2; ++mi)
        #pragma unroll
        for (int ni = 0; ni < 2; ++ni) {
            int c = wv * 32 + ni * 16 + lr;
            float hbv = Hb[c];
            #pragma unroll
            for (int r = 0; r < 4; ++r) {
                int rl = mi * 16 + lq * 4 + r;
                size_t rg = (size_t)b * 2048 + brow + rl;
                float x = acc[mi][ni][r] + hbv;
                float g = 1.f / (1.f + __expf(-x));
                float fo = FOUT[rl * 256 + c];
                float e = fo > 0.f ? fo : expm1f(fo);
                float fs = feat_src[rg * 256 + c];
                out[rg * 256 + c] = g * e + (1.f - g) * fs;
            }
        }
}

extern "C" void kernel_launch(void* const* d_in, const int* in_sizes, int n_in,
                              void* d_out, int out_size, void* d_ws, size_t ws_size,
                              hipStream_t stream) {
    const float* feat_src = (const float*)d_in[0];
    const float* feat_dst = (const float*)d_in[1];
    const float* W        = (const float*)d_in[2];
    const float* bias     = (const float*)d_in[3];
    const float* w_src    = (const float*)d_in[4];
    const float* w_dst    = (const float*)d_in[5];
    const float* Hw       = (const float*)d_in[6];
    const float* Hb       = (const float*)d_in[7];
    float* out = (float*)d_out;
    float* ws  = (float*)d_ws;

    k1_mfma<<<256, 256, 0, stream>>>(feat_src, feat_dst, W, w_src, w_dst, ws);
    kmid<<<16, 1024, 0, stream>>>(ws);
    k34<<<256, 512, 0, stream>>>(feat_src, Hw, Hb, bias, ws, out);
}

// Round 6
// 92.284 us; speedup vs baseline: 3.4308x; 1.1259x over previous
//
#include <hip/hip_runtime.h>
#include <math.h>

typedef unsigned int uint32;
typedef __attribute__((ext_vector_type(8))) short bf16x8;
typedef __attribute__((ext_vector_type(4))) float f32x4;

#define BB 4
#define HH 4
#define NSRC 2048
#define NDST 2048
#define IND 256
#define OUTD 64
#define ALPHA 0.2f
#define NB 2048           // value buckets per (b,h)
#define NCH 128           // 16-element chunks per (b,h)

// workspace layout (float offsets)
#define OFF_HDST   0            // 2097152
#define OFF_ASRC   2097152      // 32768
#define OFF_ADST   2129920      // 32768
#define OFF_PK     2162688      // 16*2048*4 = 131072 (float4 {d, w1, w2, idx*64})
#define OFF_C1     2293760      // 131072 (chunk prefix, exclusive)
#define OFF_C2     2424832      // 131072
#define OFF_CZ1    2555904      // 2048
#define OFF_CZ2    2557952      // 2048
#define OFF_T1     2560000      // 1024
#define OFF_TZ1    2561024      // 16
#define OFF_TZ2    2561040      // 16
#define OFF_BST    2561056      // 16*2049 ints
#define OFF_MM     2593840      // 16*2 (lo, inv)

__device__ __forceinline__ float fast_tanh(float x) {
    float e = __expf(2.f * x);
    return 1.f - 2.f / (e + 1.f);
}

__device__ __forceinline__ uint32 f32_to_bf16_rne(float x) {
    uint32 u = __float_as_uint(x);
    return (u + 0x7fffu + ((u >> 16) & 1u)) >> 16;
}

// split 8 f32 into bf16 hi/lo packed fragments
__device__ __forceinline__ void split8(const float* x, bf16x8& h8, bf16x8& l8) {
    uint32 hw[4], lw[4];
    #pragma unroll
    for (int p = 0; p < 4; ++p) {
        uint32 h0 = f32_to_bf16_rne(x[2 * p]);
        float f0 = __uint_as_float(h0 << 16);
        uint32 l0 = f32_to_bf16_rne(x[2 * p] - f0);
        uint32 h1 = f32_to_bf16_rne(x[2 * p + 1]);
        float f1 = __uint_as_float(h1 << 16);
        uint32 l1 = f32_to_bf16_rne(x[2 * p + 1] - f1);
        hw[p] = h0 | (h1 << 16);
        lw[p] = l0 | (l1 << 16);
    }
    h8 = *(bf16x8*)hw; l8 = *(bf16x8*)lw;
}

// K1: projection via MFMA, split-bf16 3-pass. Block: 32 rows x 4 heads
// (wave w = head w). W fragments gathered per-lane from global (L2-resident).
// grid: s(2)*b(4)*t(64) = 512 blocks, 256 threads.
__global__ __launch_bounds__(256) void k1_mfma(const float* __restrict__ feat_src,
                                               const float* __restrict__ feat_dst,
                                               const float* __restrict__ W,
                                               const float* __restrict__ w_src,
                                               const float* __restrict__ w_dst,
                                               float* __restrict__ ws) {
    __shared__ __align__(16) unsigned short Ahi[32 * 256];   // 16KB
    __shared__ __align__(16) unsigned short Alo[32 * 256];   // 16KB
    int bid = blockIdx.x;
    int t = bid & 63, b = (bid >> 6) & 3, s = bid >> 8;
    int tid = threadIdx.x;
    const float* feat = s ? feat_dst : feat_src;
    const float4* fb = (const float4*)(feat + ((size_t)b * 2048 + t * 32) * IND);
    // stage feat tile -> bf16 hi/lo LDS, XOR swizzle (byte ^= (row&7)<<4)
    #pragma unroll
    for (int it = 0; it < 8; ++it) {
        int f4 = it * 256 + tid;
        int row = f4 >> 6, c4 = f4 & 63;
        float4 v = fb[f4];
        float xs[4] = {v.x, v.y, v.z, v.w};
        uint32 hb[4], lb[4];
        #pragma unroll
        for (int j = 0; j < 4; ++j) {
            hb[j] = f32_to_bf16_rne(xs[j]);
            float hf = __uint_as_float(hb[j] << 16);
            lb[j] = f32_to_bf16_rne(xs[j] - hf);
        }
        uint2 hw, lw;
        hw.x = hb[0] | (hb[1] << 16); hw.y = hb[2] | (hb[3] << 16);
        lw.x = lb[0] | (lb[1] << 16); lw.y = lb[2] | (lb[3] << 16);
        int baddr = (row * 512 + c4 * 8) ^ ((row & 7) << 4);
        *(uint2*)((char*)Ahi + baddr) = hw;
        *(uint2*)((char*)Alo + baddr) = lw;
    }
    __syncthreads();
    int w = tid >> 6, l = tid & 63;
    int lr = l & 15, lq = l >> 4;
    const float* Wh = W + (size_t)w * 16384;
    f32x4 acc[2][4];
    #pragma unroll
    for (int mi = 0; mi < 2; ++mi)
        #pragma unroll
        for (int ni = 0; ni < 4; ++ni) acc[mi][ni] = (f32x4)0.f;
    for (int ks = 0; ks < 8; ++ks) {
        bf16x8 ah[2], al[2], bh8[4], bl8[4];
        #pragma unroll
        for (int mi = 0; mi < 2; ++mi) {
            int row = mi * 16 + lr;
            int baddr = (row * 512 + ks * 64 + lq * 16) ^ ((row & 7) << 4);
            ah[mi] = *(const bf16x8*)((const char*)Ahi + baddr);
            al[mi] = *(const bf16x8*)((const char*)Alo + baddr);
        }
        int kb = ks * 32 + lq * 8;
        #pragma unroll
        for (int ni = 0; ni < 4; ++ni) {
            const float* wp = Wh + (size_t)kb * 64 + ni * 16 + lr;
            float xv[8];
            #pragma unroll
            for (int j = 0; j < 8; ++j) xv[j] = wp[j * 64];
            split8(xv, bh8[ni], bl8[ni]);
        }
        #pragma unroll
        for (int mi = 0; mi < 2; ++mi)
            #pragma unroll
            for (int ni = 0; ni < 4; ++ni) {
                acc[mi][ni] = __builtin_amdgcn_mfma_f32_16x16x32_bf16(ah[mi], bh8[ni], acc[mi][ni], 0, 0, 0);
                acc[mi][ni] = __builtin_amdgcn_mfma_f32_16x16x32_bf16(ah[mi], bl8[ni], acc[mi][ni], 0, 0, 0);
                acc[mi][ni] = __builtin_amdgcn_mfma_f32_16x16x32_bf16(al[mi], bh8[ni], acc[mi][ni], 0, 0, 0);
            }
    }
    if (s) {
        float* hd = ws + OFF_HDST + ((size_t)(b * HH + w) * NDST + t * 32) * OUTD;
        #pragma unroll
        for (int mi = 0; mi < 2; ++mi)
            #pragma unroll
            for (int ni = 0; ni < 4; ++ni)
                #pragma unroll
                for (int r = 0; r < 4; ++r)
                    hd[(mi * 16 + lq * 4 + r) * 64 + ni * 16 + lr] = acc[mi][ni][r];
    }
    const float* wa = (s ? w_dst : w_src) + w * OUTD;
    float wa_v[4];
    #pragma unroll
    for (int ni = 0; ni < 4; ++ni) wa_v[ni] = wa[ni * 16 + lr];
    float* ap = ws + (s ? OFF_ADST : OFF_ASRC) + (b * HH + w) * NSRC + t * 32;
    #pragma unroll
    for (int mi = 0; mi < 2; ++mi)
        #pragma unroll
        for (int r = 0; r < 4; ++r) {
            float p = 0.f;
            #pragma unroll
            for (int ni = 0; ni < 4; ++ni) p += fast_tanh(acc[mi][ni][r]) * wa_v[ni];
            p += __shfl_xor(p, 1); p += __shfl_xor(p, 2);
            p += __shfl_xor(p, 4); p += __shfl_xor(p, 8);
            if (lr == 0) ap[mi * 16 + lq * 4 + r] = p;
        }
}

// KMID: per (b,h) in ONE block: bucket permutation (LDS-resident) +
// chunk-16 sums (gather h_dst) + chunk-prefix scan + packed PK dump.
// grid: 16 blocks, 1024 threads.
__global__ __launch_bounds__(1024) void kmid(float* __restrict__ ws) {
    __shared__ float keys[2048];
    __shared__ int   hist[2048];      // counts -> reused as scatter cursors
    __shared__ float keysP[2048];
    __shared__ int   idxP[2048];
    __shared__ float w1L[2048];
    __shared__ float w2L[2048];
    __shared__ float CZ1L[128], CZ2L[128];
    __shared__ float ST1[16 * 64], ST2[16 * 64];
    __shared__ float SZ1[16], SZ2[16];
    __shared__ float red[32];
    __shared__ float loinv[2];
    __shared__ int wtot[16];
    int bh = blockIdx.x, tid = threadIdx.x;
    int lane = tid & 63, wv = tid >> 6;
    const float* ad = ws + OFF_ADST + bh * NDST;
    float d0 = ad[tid], d1 = ad[tid + 1024];
    keys[tid] = d0; keys[tid + 1024] = d1;
    float mn = fminf(d0, d1), mx = fmaxf(d0, d1);
    #pragma unroll
    for (int off = 32; off; off >>= 1) {
        mn = fminf(mn, __shfl_xor(mn, off));
        mx = fmaxf(mx, __shfl_xor(mx, off));
    }
    if (lane == 0) { red[wv] = mn; red[16 + wv] = mx; }
    hist[tid] = 0; hist[tid + 1024] = 0;
    __syncthreads();
    if (tid == 0) {
        float lo = red[0], hi = red[16];
        #pragma unroll
        for (int i = 1; i < 16; ++i) { lo = fminf(lo, red[i]); hi = fmaxf(hi, red[16 + i]); }
        float wd = hi - lo;
        float inv = (float)NB / (wd + wd * 1e-6f + 1e-30f);
        loinv[0] = lo; loinv[1] = inv;
        ws[OFF_MM + bh * 2] = lo; ws[OFF_MM + bh * 2 + 1] = inv;
    }
    __syncthreads();
    float lo = loinv[0], inv = loinv[1];
    int b0 = (int)((d0 - lo) * inv); b0 = b0 < 0 ? 0 : (b0 > NB - 1 ? NB - 1 : b0);
    int b1 = (int)((d1 - lo) * inv); b1 = b1 < 0 ? 0 : (b1 > NB - 1 ? NB - 1 : b1);
    atomicAdd(&hist[b0], 1);
    atomicAdd(&hist[b1], 1);
    __syncthreads();
    int h0 = hist[2 * tid], h1 = hist[2 * tid + 1];
    int s = h0 + h1, sc = s;
    #pragma unroll
    for (int off = 1; off < 64; off <<= 1) {
        int v = __shfl_up(sc, off);
        if (lane >= off) sc += v;
    }
    if (lane == 63) wtot[wv] = sc;
    __syncthreads();
    if (tid == 0) {
        int r = 0;
        #pragma unroll
        for (int i = 0; i < 16; ++i) { int v = wtot[i]; wtot[i] = r; r += v; }
    }
    __syncthreads();
    int base = wtot[wv] + (sc - s);
    int* bstg = (int*)(ws + OFF_BST) + bh * (NB + 1);
    hist[2 * tid] = base;
    hist[2 * tid + 1] = base + h0;
    bstg[2 * tid] = base;
    bstg[2 * tid + 1] = base + h0;
    if (tid == 0) bstg[NB] = NDST;
    __syncthreads();
    int p0 = atomicAdd(&hist[b0], 1);
    keysP[p0] = d0; idxP[p0] = tid;
    w1L[p0] = __expf(d0); w2L[p0] = __expf(ALPHA * d0);
    int p1 = atomicAdd(&hist[b1], 1);
    keysP[p1] = d1; idxP[p1] = tid + 1024;
    w1L[p1] = __expf(d1); w2L[p1] = __expf(ALPHA * d1);
    __syncthreads();
    // packed PK dump: {d, w1, w2, idx*64 (int bits)}
    {
        float4* pkg = (float4*)(ws + OFF_PK) + (size_t)bh * 2048;
        pkg[tid] = make_float4(keysP[tid], w1L[tid], w2L[tid],
                               __int_as_float(idxP[tid] * 64));
        pkg[tid + 1024] = make_float4(keysP[tid + 1024], w1L[tid + 1024], w2L[tid + 1024],
                                      __int_as_float(idxP[tid + 1024] * 64));
    }
    // chunk-16 sums: wave wv owns chunks wv*8..wv*8+8, lane = o
    const float* hd = ws + OFF_HDST + (size_t)bh * NDST * OUTD;
    float* C1g = ws + OFF_C1 + (size_t)bh * NCH * 64;
    float* C2g = ws + OFF_C2 + (size_t)bh * NCH * 64;
    int o = lane;
    float csum1[8], csum2[8];
    #pragma unroll
    for (int k = 0; k < 8; ++k) {
        int c = wv * 8 + k;
        float c1 = 0.f, c2 = 0.f, cz1 = 0.f, cz2 = 0.f;
        #pragma unroll 4
        for (int ii = 0; ii < 16; ++ii) {
            int i = c * 16 + ii;
            int m = idxP[i];
            float w1 = w1L[i], w2 = w2L[i];
            float hv = hd[m * 64 + o];
            c1 += w1 * hv; c2 += w2 * hv; cz1 += w1; cz2 += w2;
        }
        csum1[k] = c1; csum2[k] = c2;
        if (o == 0) { CZ1L[c] = cz1; CZ2L[c] = cz2; }
    }
    float run1 = 0.f, run2 = 0.f;
    float sv1[8], sv2[8];
    #pragma unroll
    for (int q = 0; q < 8; ++q) {
        sv1[q] = run1; sv2[q] = run2;
        run1 += csum1[q]; run2 += csum2[q];
    }
    ST1[wv * 64 + o] = run1; ST2[wv * 64 + o] = run2;
    float rz1 = 0.f, rz2 = 0.f;
    float zv1[8], zv2[8];
    __syncthreads();
    if (lane == 0) {
        #pragma unroll
        for (int q = 0; q < 8; ++q) {
            int c = wv * 8 + q;
            zv1[q] = rz1; zv2[q] = rz2;
            rz1 += CZ1L[c]; rz2 += CZ2L[c];
        }
        SZ1[wv] = rz1; SZ2[wv] = rz2;
    }
    __syncthreads();
    float base1 = 0.f, base2 = 0.f;
    for (int ss = 0; ss < wv; ++ss) { base1 += ST1[ss * 64 + o]; base2 += ST2[ss * 64 + o]; }
    #pragma unroll
    for (int q = 0; q < 8; ++q) {
        int c = wv * 8 + q;
        C1g[c * 64 + o] = base1 + sv1[q];
        C2g[c * 64 + o] = base2 + sv2[q];
    }
    if (wv == 15) ws[OFF_T1 + bh * 64 + o] = base1 + run1;
    if (lane == 0) {
        float zb1 = 0.f, zb2 = 0.f;
        for (int ss = 0; ss < wv; ++ss) { zb1 += SZ1[ss]; zb2 += SZ2[ss]; }
        #pragma unroll
        for (int q = 0; q < 8; ++q) {
            int c = wv * 8 + q;
            ws[OFF_CZ1 + bh * NCH + c] = zb1 + zv1[q];
            ws[OFF_CZ2 + bh * NCH + c] = zb2 + zv2[q];
        }
        if (wv == 15) { ws[OFF_TZ1 + bh] = zb1 + rz1; ws[OFF_TZ2 + bh] = zb2 + rz2; }
    }
}

// K34: fused attention-output + gate. Block: 16 src rows x 256 cols, 8 waves.
// Phase1: wave wv owns head h=wv>>1, 8 n-rows; lane-parallel scalar prefetch,
// prefetched C1/C2 rows, packed-quad remainder. Phase2: gate MFMA + epilogue.
// grid: b(4)*ntile(128) = 512 blocks, 512 threads.
#define FSTR 264
__global__ __launch_bounds__(512) void k34(const float* __restrict__ feat_src,
                                           const float* __restrict__ Hw,
                                           const float* __restrict__ Hb,
                                           const float* __restrict__ bias,
                                           const float* __restrict__ ws,
                                           float* __restrict__ out) {
    __shared__ float FOUT[16 * FSTR];                       // 16.5KB
    __shared__ __align__(16) unsigned short Ahi[16 * 256];  // 8KB
    __shared__ __align__(16) unsigned short Alo[16 * 256];  // 8KB
    int bid = blockIdx.x;
    int b = bid >> 7, brow = (bid & 127) * 16;
    int tid = threadIdx.x;
    int o = tid & 63;
    int wv = __builtin_amdgcn_readfirstlane(tid >> 6);
    // phase 0: stage 16 feat rows as bf16 hi/lo
    const float4* fb = (const float4*)(feat_src + ((size_t)b * 2048 + brow) * IND);
    #pragma unroll
    for (int it = 0; it < 2; ++it) {
        int f4 = it * 512 + tid;
        int row = f4 >> 6, c4 = f4 & 63;
        float4 v = fb[f4];
        float xs[4] = {v.x, v.y, v.z, v.w};
        uint32 hb[4], lb[4];
        #pragma unroll
        for (int j = 0; j < 4; ++j) {
            hb[j] = f32_to_bf16_rne(xs[j]);
            float hf = __uint_as_float(hb[j] << 16);
            lb[j] = f32_to_bf16_rne(xs[j] - hf);
        }
        uint2 hw, lw;
        hw.x = hb[0] | (hb[1] << 16); hw.y = hb[2] | (hb[3] << 16);
        lw.x = lb[0] | (lb[1] << 16); lw.y = lb[2] | (lb[3] << 16);
        int baddr = (row * 512 + c4 * 8) ^ ((row & 7) << 4);
        *(uint2*)((char*)Ahi + baddr) = hw;
        *(uint2*)((char*)Alo + baddr) = lw;
    }
    // phase 1: head fixed per wave; 8 rows, lane-parallel scalar prefetch
    {
        int h = wv >> 1;
        int bh = b * 4 + h;
        int nbase = (wv & 1) * 8;
        // wave-uniform hoists
        float T1v = ws[OFF_T1 + bh * 64 + o];
        float tz1 = ws[OFF_TZ1 + bh], tz2 = ws[OFF_TZ2 + bh];
        float blo = ws[OFF_MM + bh * 2], binv = ws[OFF_MM + bh * 2 + 1];
        float biasv = bias[o];
        // lane r (r = o&7) prefetches row r's scalar chain
        int r_l = o & 7;
        float t_l = ws[OFF_ASRC + bh * 2048 + brow + nbase + r_l];
        float th_l = -t_l;
        int bk = (int)floorf((th_l - blo) * binv);
        bk = bk < 0 ? 0 : (bk > NB - 1 ? NB - 1 : bk);
        const int* bst = (const int*)(ws + OFF_BST) + bh * (NB + 1);
        int jstart = bst[bk], jend = bst[bk + 1];
        int cch = (jstart + 8) >> 4; if (cch > NCH - 1) cch = NCH - 1;
        int i0c_l = cch << 4;
        int lo2_l = i0c_l < jstart ? i0c_l : jstart;
        int hi2_l = i0c_l > jend ? i0c_l : jend;
        float czp1_l = ws[OFF_CZ1 + bh * NCH + cch];
        float czp2_l = ws[OFF_CZ2 + bh * NCH + cch];
        // prefetch all 8 rows' C1/C2 prefix rows (independent 64-wide loads)
        float c1v[8], c2v[8];
        #pragma unroll
        for (int r = 0; r < 8; ++r) {
            int cch_r = __shfl(cch, r);
            c1v[r] = ws[OFF_C1 + ((size_t)bh * NCH + cch_r) * 64 + o];
            c2v[r] = ws[OFF_C2 + ((size_t)bh * NCH + cch_r) * 64 + o];
        }
        const float4* pk = (const float4*)(ws + OFF_PK) + (size_t)bh * 2048;
        const float* hd = ws + OFF_HDST + (size_t)bh * NDST * OUTD;
        for (int r = 0; r < 8; ++r) {
            float t_r = __shfl(t_l, r);
            float th = -t_r;
            int i0c = __shfl(i0c_l, r);
            int lo2 = __shfl(lo2_l, r);
            int hi2 = __shfl(hi2_l, r);
            float p1 = c1v[r], p2 = c2v[r];
            float zp1 = __shfl(czp1_l, r), zp2 = __shfl(czp2_l, r);
            for (int i = lo2; i < hi2; ++i) {
                float4 q = pk[i];
                float sel = (q.x <= th ? 1.f : 0.f) - (i < i0c ? 1.f : 0.f);
                int m64 = __float_as_int(q.w);
                float hv = hd[m64 + o];
                float w1 = q.y * sel, w2 = q.z * sel;
                p1 += w1 * hv; p2 += w2 * hv; zp1 += w1; zp2 += w2;
            }
            float et = __expf(t_r), et2 = __expf(ALPHA * t_r);
            float num = et * (T1v - p1) + et2 * p2;
            float den = et * (tz1 - zp1) + et2 * zp2;
            FOUT[(nbase + r) * FSTR + h * 64 + o] = num / den + biasv;
        }
    }
    __syncthreads();
    // phase 2: gate GEMM, wave wv -> cols wv*32..+32, rows 0..15, K=256
    int l = tid & 63;
    int lr = l & 15, lq = l >> 4;
    f32x4 acc[2];
    acc[0] = (f32x4)0.f; acc[1] = (f32x4)0.f;
    for (int ks = 0; ks < 8; ++ks) {
        bf16x8 ah, al, bh8[2], bl8[2];
        {
            int row = lr;
            int baddr = (row * 512 + ks * 64 + lq * 16) ^ ((row & 7) << 4);
            ah = *(const bf16x8*)((const char*)Ahi + baddr);
            al = *(const bf16x8*)((const char*)Alo + baddr);
        }
        int kb = ks * 32 + lq * 8;
        #pragma unroll
        for (int ni = 0; ni < 2; ++ni) {
            int col = wv * 32 + ni * 16 + lr;
            const float4* hp = (const float4*)(Hw + (size_t)col * 256 + kb);
            float4 va = hp[0], vb = hp[1];
            float xv[8] = {va.x, va.y, va.z, va.w, vb.x, vb.y, vb.z, vb.w};
            split8(xv, bh8[ni], bl8[ni]);
        }
        #pragma unroll
        for (int ni = 0; ni < 2; ++ni) {
            acc[ni] = __builtin_amdgcn_mfma_f32_16x16x32_bf16(ah, bh8[ni], acc[ni], 0, 0, 0);
            acc[ni] = __builtin_amdgcn_mfma_f32_16x16x32_bf16(ah, bl8[ni], acc[ni], 0, 0, 0);
            acc[ni] = __builtin_amdgcn_mfma_f32_16x16x32_bf16(al, bh8[ni], acc[ni], 0, 0, 0);
        }
    }
    // epilogue: gate + elu + mix
    #pragma unroll
    for (int ni = 0; ni < 2; ++ni) {
        int c = wv * 32 + ni * 16 + lr;
        float hbv = Hb[c];
        #pragma unroll
        for (int r = 0; r < 4; ++r) {
            int rl = lq * 4 + r;
            size_t rg = (size_t)b * 2048 + brow + rl;
            float x = acc[ni][r] + hbv;
            float g = 1.f / (1.f + __expf(-x));
            float fo = FOUT[rl * FSTR + c];
            float e = fo > 0.f ? fo : expm1f(fo);
            float fs = feat_src[rg * 256 + c];
            out[rg * 256 + c] = g * e + (1.f - g) * fs;
        }
    }
}

extern "C" void kernel_launch(void* const* d_in, const int* in_sizes, int n_in,
                              void* d_out, int out_size, void* d_ws, size_t ws_size,
                              hipStream_t stream) {
    const float* feat_src = (const float*)d_in[0];
    const float* feat_dst = (const float*)d_in[1];
    const float* W        = (const float*)d_in[2];
    const float* bias     = (const float*)d_in[3];
    const float* w_src    = (const float*)d_in[4];
    const float* w_dst    = (const float*)d_in[5];
    const float* Hw       = (const float*)d_in[6];
    const float* Hb       = (const float*)d_in[7];
    float* out = (float*)d_out;
    float* ws  = (float*)d_ws;

    k1_mfma<<<512, 256, 0, stream>>>(feat_src, feat_dst, W, w_src, w_dst, ws);
    kmid<<<16, 1024, 0, stream>>>(ws);
    k34<<<512, 512, 0, stream>>>(feat_src, Hw, Hb, bias, ws, out);
}

// Round 7
// 87.752 us; speedup vs baseline: 3.6080x; 1.0516x over previous
//
#include <hip/hip_runtime.h>
#include <math.h>

typedef unsigned int uint32;
typedef __attribute__((ext_vector_type(8))) short bf16x8;
typedef __attribute__((ext_vector_type(4))) float f32x4;

#define BB 4
#define HH 4
#define NSRC 2048
#define NDST 2048
#define IND 256
#define OUTD 64
#define ALPHA 0.2f
#define NB 2048           // value buckets per (b,h)
#define NCH 128           // 16-element chunks per (b,h)

// workspace layout (float offsets)
#define OFF_HDST   0            // 2097152
#define OFF_ASRC   2097152      // 32768
#define OFF_ADST   2129920      // 32768
#define OFF_PK     2162688      // 16*2048*4 = 131072 (float4 {d, w1, w2, idx*64})
#define OFF_C1     2293760      // 131072 (chunk prefix, exclusive)
#define OFF_C2     2424832      // 131072
#define OFF_CZ1    2555904      // 2048
#define OFF_CZ2    2557952      // 2048
#define OFF_T1     2560000      // 1024
#define OFF_TZ1    2561024      // 16
#define OFF_TZ2    2561040      // 16
#define OFF_BST    2561056      // 16*2049 ints
#define OFF_MM     2593840      // 16*2 (lo, inv)

__device__ __forceinline__ float fast_tanh(float x) {
    float e = __expf(2.f * x);
    return 1.f - 2.f / (e + 1.f);
}

__device__ __forceinline__ uint32 f32_to_bf16_rne(float x) {
    uint32 u = __float_as_uint(x);
    return (u + 0x7fffu + ((u >> 16) & 1u)) >> 16;
}

// split 8 f32 into bf16 hi/lo packed fragments
__device__ __forceinline__ void split8(const float* x, bf16x8& h8, bf16x8& l8) {
    uint32 hw[4], lw[4];
    #pragma unroll
    for (int p = 0; p < 4; ++p) {
        uint32 h0 = f32_to_bf16_rne(x[2 * p]);
        float f0 = __uint_as_float(h0 << 16);
        uint32 l0 = f32_to_bf16_rne(x[2 * p] - f0);
        uint32 h1 = f32_to_bf16_rne(x[2 * p + 1]);
        float f1 = __uint_as_float(h1 << 16);
        uint32 l1 = f32_to_bf16_rne(x[2 * p + 1] - f1);
        hw[p] = h0 | (h1 << 16);
        lw[p] = l0 | (l1 << 16);
    }
    h8 = *(bf16x8*)hw; l8 = *(bf16x8*)lw;
}

// K1: projection via MFMA, split-bf16 3-pass. Block: 32 rows x 4 heads
// (wave w = head w). W fragments gathered per-lane from global (L2-resident).
// grid: s(2)*b(4)*t(64) = 512 blocks, 256 threads.
__global__ __launch_bounds__(256) void k1_mfma(const float* __restrict__ feat_src,
                                               const float* __restrict__ feat_dst,
                                               const float* __restrict__ W,
                                               const float* __restrict__ w_src,
                                               const float* __restrict__ w_dst,
                                               float* __restrict__ ws) {
    __shared__ __align__(16) unsigned short Ahi[32 * 256];   // 16KB
    __shared__ __align__(16) unsigned short Alo[32 * 256];   // 16KB
    int bid = blockIdx.x;
    int t = bid & 63, b = (bid >> 6) & 3, s = bid >> 8;
    int tid = threadIdx.x;
    const float* feat = s ? feat_dst : feat_src;
    const float4* fb = (const float4*)(feat + ((size_t)b * 2048 + t * 32) * IND);
    // stage feat tile -> bf16 hi/lo LDS, XOR swizzle (byte ^= (row&7)<<4)
    #pragma unroll
    for (int it = 0; it < 8; ++it) {
        int f4 = it * 256 + tid;
        int row = f4 >> 6, c4 = f4 & 63;
        float4 v = fb[f4];
        float xs[4] = {v.x, v.y, v.z, v.w};
        uint32 hb[4], lb[4];
        #pragma unroll
        for (int j = 0; j < 4; ++j) {
            hb[j] = f32_to_bf16_rne(xs[j]);
            float hf = __uint_as_float(hb[j] << 16);
            lb[j] = f32_to_bf16_rne(xs[j] - hf);
        }
        uint2 hw, lw;
        hw.x = hb[0] | (hb[1] << 16); hw.y = hb[2] | (hb[3] << 16);
        lw.x = lb[0] | (lb[1] << 16); lw.y = lb[2] | (lb[3] << 16);
        int baddr = (row * 512 + c4 * 8) ^ ((row & 7) << 4);
        *(uint2*)((char*)Ahi + baddr) = hw;
        *(uint2*)((char*)Alo + baddr) = lw;
    }
    __syncthreads();
    int w = tid >> 6, l = tid & 63;
    int lr = l & 15, lq = l >> 4;
    const float* Wh = W + (size_t)w * 16384;
    f32x4 acc[2][4];
    #pragma unroll
    for (int mi = 0; mi < 2; ++mi)
        #pragma unroll
        for (int ni = 0; ni < 4; ++ni) acc[mi][ni] = (f32x4)0.f;
    for (int ks = 0; ks < 8; ++ks) {
        bf16x8 ah[2], al[2], bh8[4], bl8[4];
        #pragma unroll
        for (int mi = 0; mi < 2; ++mi) {
            int row = mi * 16 + lr;
            int baddr = (row * 512 + ks * 64 + lq * 16) ^ ((row & 7) << 4);
            ah[mi] = *(const bf16x8*)((const char*)Ahi + baddr);
            al[mi] = *(const bf16x8*)((const char*)Alo + baddr);
        }
        int kb = ks * 32 + lq * 8;
        #pragma unroll
        for (int ni = 0; ni < 4; ++ni) {
            const float* wp = Wh + (size_t)kb * 64 + ni * 16 + lr;
            float xv[8];
            #pragma unroll
            for (int j = 0; j < 8; ++j) xv[j] = wp[j * 64];
            split8(xv, bh8[ni], bl8[ni]);
        }
        #pragma unroll
        for (int mi = 0; mi < 2; ++mi)
            #pragma unroll
            for (int ni = 0; ni < 4; ++ni) {
                acc[mi][ni] = __builtin_amdgcn_mfma_f32_16x16x32_bf16(ah[mi], bh8[ni], acc[mi][ni], 0, 0, 0);
                acc[mi][ni] = __builtin_amdgcn_mfma_f32_16x16x32_bf16(ah[mi], bl8[ni], acc[mi][ni], 0, 0, 0);
                acc[mi][ni] = __builtin_amdgcn_mfma_f32_16x16x32_bf16(al[mi], bh8[ni], acc[mi][ni], 0, 0, 0);
            }
    }
    if (s) {
        float* hd = ws + OFF_HDST + ((size_t)(b * HH + w) * NDST + t * 32) * OUTD;
        #pragma unroll
        for (int mi = 0; mi < 2; ++mi)
            #pragma unroll
            for (int ni = 0; ni < 4; ++ni)
                #pragma unroll
                for (int r = 0; r < 4; ++r)
                    hd[(mi * 16 + lq * 4 + r) * 64 + ni * 16 + lr] = acc[mi][ni][r];
    }
    const float* wa = (s ? w_dst : w_src) + w * OUTD;
    float wa_v[4];
    #pragma unroll
    for (int ni = 0; ni < 4; ++ni) wa_v[ni] = wa[ni * 16 + lr];
    float* ap = ws + (s ? OFF_ADST : OFF_ASRC) + (b * HH + w) * NSRC + t * 32;
    #pragma unroll
    for (int mi = 0; mi < 2; ++mi)
        #pragma unroll
        for (int r = 0; r < 4; ++r) {
            float p = 0.f;
            #pragma unroll
            for (int ni = 0; ni < 4; ++ni) p += fast_tanh(acc[mi][ni][r]) * wa_v[ni];
            p += __shfl_xor(p, 1); p += __shfl_xor(p, 2);
            p += __shfl_xor(p, 4); p += __shfl_xor(p, 8);
            if (lr == 0) ap[mi * 16 + lq * 4 + r] = p;
        }
}

// KMID: per (b,h) in ONE block: bucket permutation (LDS-resident) +
// chunk-16 sums (gather h_dst) + chunk-prefix scan + packed PK dump.
// grid: 16 blocks, 1024 threads.
__global__ __launch_bounds__(1024) void kmid(float* __restrict__ ws) {
    __shared__ float keys[2048];
    __shared__ int   hist[2048];      // counts -> reused as scatter cursors
    __shared__ float keysP[2048];
    __shared__ int   idxP[2048];
    __shared__ float w1L[2048];
    __shared__ float w2L[2048];
    __shared__ float CZ1L[128], CZ2L[128];
    __shared__ float ST1[16 * 64], ST2[16 * 64];
    __shared__ float SZ1[16], SZ2[16];
    __shared__ float red[32];
    __shared__ float loinv[2];
    __shared__ int wtot[16];
    int bh = blockIdx.x, tid = threadIdx.x;
    int lane = tid & 63, wv = tid >> 6;
    const float* ad = ws + OFF_ADST + bh * NDST;
    float d0 = ad[tid], d1 = ad[tid + 1024];
    keys[tid] = d0; keys[tid + 1024] = d1;
    float mn = fminf(d0, d1), mx = fmaxf(d0, d1);
    #pragma unroll
    for (int off = 32; off; off >>= 1) {
        mn = fminf(mn, __shfl_xor(mn, off));
        mx = fmaxf(mx, __shfl_xor(mx, off));
    }
    if (lane == 0) { red[wv] = mn; red[16 + wv] = mx; }
    hist[tid] = 0; hist[tid + 1024] = 0;
    __syncthreads();
    if (tid == 0) {
        float lo = red[0], hi = red[16];
        #pragma unroll
        for (int i = 1; i < 16; ++i) { lo = fminf(lo, red[i]); hi = fmaxf(hi, red[16 + i]); }
        float wd = hi - lo;
        float inv = (float)NB / (wd + wd * 1e-6f + 1e-30f);
        loinv[0] = lo; loinv[1] = inv;
        ws[OFF_MM + bh * 2] = lo; ws[OFF_MM + bh * 2 + 1] = inv;
    }
    __syncthreads();
    float lo = loinv[0], inv = loinv[1];
    int b0 = (int)((d0 - lo) * inv); b0 = b0 < 0 ? 0 : (b0 > NB - 1 ? NB - 1 : b0);
    int b1 = (int)((d1 - lo) * inv); b1 = b1 < 0 ? 0 : (b1 > NB - 1 ? NB - 1 : b1);
    atomicAdd(&hist[b0], 1);
    atomicAdd(&hist[b1], 1);
    __syncthreads();
    int h0 = hist[2 * tid], h1 = hist[2 * tid + 1];
    int s = h0 + h1, sc = s;
    #pragma unroll
    for (int off = 1; off < 64; off <<= 1) {
        int v = __shfl_up(sc, off);
        if (lane >= off) sc += v;
    }
    if (lane == 63) wtot[wv] = sc;
    __syncthreads();
    if (tid == 0) {
        int r = 0;
        #pragma unroll
        for (int i = 0; i < 16; ++i) { int v = wtot[i]; wtot[i] = r; r += v; }
    }
    __syncthreads();
    int base = wtot[wv] + (sc - s);
    int* bstg = (int*)(ws + OFF_BST) + bh * (NB + 1);
    hist[2 * tid] = base;
    hist[2 * tid + 1] = base + h0;
    bstg[2 * tid] = base;
    bstg[2 * tid + 1] = base + h0;
    if (tid == 0) bstg[NB] = NDST;
    __syncthreads();
    int p0 = atomicAdd(&hist[b0], 1);
    keysP[p0] = d0; idxP[p0] = tid;
    w1L[p0] = __expf(d0); w2L[p0] = __expf(ALPHA * d0);
    int p1 = atomicAdd(&hist[b1], 1);
    keysP[p1] = d1; idxP[p1] = tid + 1024;
    w1L[p1] = __expf(d1); w2L[p1] = __expf(ALPHA * d1);
    __syncthreads();
    // packed PK dump: {d, w1, w2, idx*64 (int bits)}
    {
        float4* pkg = (float4*)(ws + OFF_PK) + (size_t)bh * 2048;
        pkg[tid] = make_float4(keysP[tid], w1L[tid], w2L[tid],
                               __int_as_float(idxP[tid] * 64));
        pkg[tid + 1024] = make_float4(keysP[tid + 1024], w1L[tid + 1024], w2L[tid + 1024],
                                      __int_as_float(idxP[tid + 1024] * 64));
    }
    // chunk-16 sums: wave wv owns chunks wv*8..wv*8+8, lane = o
    const float* hd = ws + OFF_HDST + (size_t)bh * NDST * OUTD;
    float* C1g = ws + OFF_C1 + (size_t)bh * NCH * 64;
    float* C2g = ws + OFF_C2 + (size_t)bh * NCH * 64;
    int o = lane;
    float csum1[8], csum2[8];
    #pragma unroll
    for (int k = 0; k < 8; ++k) {
        int c = wv * 8 + k;
        float c1 = 0.f, c2 = 0.f, cz1 = 0.f, cz2 = 0.f;
        #pragma unroll 4
        for (int ii = 0; ii < 16; ++ii) {
            int i = c * 16 + ii;
            int m = idxP[i];
            float w1 = w1L[i], w2 = w2L[i];
            float hv = hd[m * 64 + o];
            c1 += w1 * hv; c2 += w2 * hv; cz1 += w1; cz2 += w2;
        }
        csum1[k] = c1; csum2[k] = c2;
        if (o == 0) { CZ1L[c] = cz1; CZ2L[c] = cz2; }
    }
    float run1 = 0.f, run2 = 0.f;
    float sv1[8], sv2[8];
    #pragma unroll
    for (int q = 0; q < 8; ++q) {
        sv1[q] = run1; sv2[q] = run2;
        run1 += csum1[q]; run2 += csum2[q];
    }
    ST1[wv * 64 + o] = run1; ST2[wv * 64 + o] = run2;
    float rz1 = 0.f, rz2 = 0.f;
    float zv1[8], zv2[8];
    __syncthreads();
    if (lane == 0) {
        #pragma unroll
        for (int q = 0; q < 8; ++q) {
            int c = wv * 8 + q;
            zv1[q] = rz1; zv2[q] = rz2;
            rz1 += CZ1L[c]; rz2 += CZ2L[c];
        }
        SZ1[wv] = rz1; SZ2[wv] = rz2;
    }
    __syncthreads();
    float base1 = 0.f, base2 = 0.f;
    for (int ss = 0; ss < wv; ++ss) { base1 += ST1[ss * 64 + o]; base2 += ST2[ss * 64 + o]; }
    #pragma unroll
    for (int q = 0; q < 8; ++q) {
        int c = wv * 8 + q;
        C1g[c * 64 + o] = base1 + sv1[q];
        C2g[c * 64 + o] = base2 + sv2[q];
    }
    if (wv == 15) ws[OFF_T1 + bh * 64 + o] = base1 + run1;
    if (lane == 0) {
        float zb1 = 0.f, zb2 = 0.f;
        for (int ss = 0; ss < wv; ++ss) { zb1 += SZ1[ss]; zb2 += SZ2[ss]; }
        #pragma unroll
        for (int q = 0; q < 8; ++q) {
            int c = wv * 8 + q;
            ws[OFF_CZ1 + bh * NCH + c] = zb1 + zv1[q];
            ws[OFF_CZ2 + bh * NCH + c] = zb2 + zv2[q];
        }
        if (wv == 15) { ws[OFF_TZ1 + bh] = zb1 + rz1; ws[OFF_TZ2 + bh] = zb2 + rz2; }
    }
}

// K34: fused attention-output + gate. Block: 8 src rows x 256 cols, 8 waves.
// Phase1: wave wv owns head h=wv>>1, 4 n-rows; uniform (SGPR) row state,
// batched 8-deep remainder pipeline (s_load pk quads -> hd gathers -> acc).
// Phase2: gate MFMA (M=8 of 16) + fused epilogue.
// grid: b(4)*ntile(256) = 1024 blocks, 512 threads.
#define FSTR 260
__global__ __launch_bounds__(512) void k34(const float* __restrict__ feat_src,
                                           const float* __restrict__ Hw,
                                           const float* __restrict__ Hb,
                                           const float* __restrict__ bias,
                                           const float* __restrict__ ws,
                                           float* __restrict__ out) {
    __shared__ float FOUT[8 * FSTR];                       // 8.3KB
    __shared__ __align__(16) unsigned short Ahi[8 * 256];  // 4KB
    __shared__ __align__(16) unsigned short Alo[8 * 256];  // 4KB
    int bid = blockIdx.x;
    int b = bid >> 8, brow = (bid & 255) * 8;
    int tid = threadIdx.x;
    int o = tid & 63;
    int wv = __builtin_amdgcn_readfirstlane(tid >> 6);
    // phase 0: stage 8 feat rows as bf16 hi/lo (512 float4, 1 per thread)
    const float4* fb = (const float4*)(feat_src + ((size_t)b * 2048 + brow) * IND);
    {
        int f4 = tid;
        int row = f4 >> 6, c4 = f4 & 63;
        float4 v = fb[f4];
        float xs[4] = {v.x, v.y, v.z, v.w};
        uint32 hb[4], lb[4];
        #pragma unroll
        for (int j = 0; j < 4; ++j) {
            hb[j] = f32_to_bf16_rne(xs[j]);
            float hf = __uint_as_float(hb[j] << 16);
            lb[j] = f32_to_bf16_rne(xs[j] - hf);
        }
        uint2 hw, lw;
        hw.x = hb[0] | (hb[1] << 16); hw.y = hb[2] | (hb[3] << 16);
        lw.x = lb[0] | (lb[1] << 16); lw.y = lb[2] | (lb[3] << 16);
        int baddr = (row * 512 + c4 * 8) ^ ((row & 7) << 4);
        *(uint2*)((char*)Ahi + baddr) = hw;
        *(uint2*)((char*)Alo + baddr) = lw;
    }
    // phase 1: head fixed per wave; 4 rows, lane-parallel scalar prefetch
    {
        int h = wv >> 1;
        int bh = b * 4 + h;
        int nbase = (wv & 1) * 4;
        // wave-uniform hoists
        float T1v = ws[OFF_T1 + bh * 64 + o];
        float tz1 = ws[OFF_TZ1 + bh], tz2 = ws[OFF_TZ2 + bh];
        float blo = ws[OFF_MM + bh * 2], binv = ws[OFF_MM + bh * 2 + 1];
        float biasv = bias[o];
        // lane r (r = o&3) prefetches row r's scalar chain
        int r_l = o & 3;
        float t_l = ws[OFF_ASRC + bh * 2048 + brow + nbase + r_l];
        float th_l = -t_l;
        int bk = (int)floorf((th_l - blo) * binv);
        bk = bk < 0 ? 0 : (bk > NB - 1 ? NB - 1 : bk);
        const int* bst = (const int*)(ws + OFF_BST) + bh * (NB + 1);
        int jstart = bst[bk], jend = bst[bk + 1];
        int cch = (jstart + 8) >> 4; if (cch > NCH - 1) cch = NCH - 1;
        int i0c_l = cch << 4;
        int lo2_l = i0c_l < jstart ? i0c_l : jstart;
        int hi2_l = i0c_l > jend ? i0c_l : jend;
        float czp1_l = ws[OFF_CZ1 + bh * NCH + cch];
        float czp2_l = ws[OFF_CZ2 + bh * NCH + cch];
        // prefetch all 4 rows' C1/C2 prefix rows (independent 64-wide loads)
        float c1v[4], c2v[4];
        #pragma unroll
        for (int r = 0; r < 4; ++r) {
            int cch_r = __builtin_amdgcn_readfirstlane(__shfl(cch, r));
            c1v[r] = ws[OFF_C1 + ((size_t)bh * NCH + cch_r) * 64 + o];
            c2v[r] = ws[OFF_C2 + ((size_t)bh * NCH + cch_r) * 64 + o];
        }
        const float4* pk = (const float4*)(ws + OFF_PK) + (size_t)bh * 2048;
        const float* hd = ws + OFF_HDST + (size_t)bh * NDST * OUTD;
        for (int r = 0; r < 4; ++r) {
            float t_r = __uint_as_float(
                __builtin_amdgcn_readfirstlane(__float_as_uint(__shfl(t_l, r))));
            float th = -t_r;
            int i0c = __builtin_amdgcn_readfirstlane(__shfl(i0c_l, r));
            int lo2 = __builtin_amdgcn_readfirstlane(__shfl(lo2_l, r));
            int hi2 = __builtin_amdgcn_readfirstlane(__shfl(hi2_l, r));
            float p1 = c1v[r], p2 = c2v[r];
            float zp1 = __shfl(czp1_l, r), zp2 = __shfl(czp2_l, r);
            // batched 8-deep remainder: all pk s_loads, then all hd gathers
            for (int i = lo2; i < hi2; i += 8) {
                float4 q[8];
                #pragma unroll
                for (int j = 0; j < 8; ++j) {
                    int ii = i + j < hi2 ? i + j : hi2 - 1;   // uniform (SGPR)
                    q[j] = pk[ii];
                }
                float hv[8];
                #pragma unroll
                for (int j = 0; j < 8; ++j)
                    hv[j] = hd[__float_as_int(q[j].w) + o];
                #pragma unroll
                for (int j = 0; j < 8; ++j) {
                    float sel = (q[j].x <= th ? 1.f : 0.f) - (i + j < i0c ? 1.f : 0.f);
                    sel = (i + j < hi2) ? sel : 0.f;
                    float w1 = q[j].y * sel, w2 = q[j].z * sel;
                    p1 += w1 * hv[j]; p2 += w2 * hv[j]; zp1 += w1; zp2 += w2;
                }
            }
            float et = __expf(t_r), et2 = __expf(ALPHA * t_r);
            float num = et * (T1v - p1) + et2 * p2;
            float den = et * (tz1 - zp1) + et2 * zp2;
            FOUT[(nbase + r) * FSTR + h * 64 + o] = num / den + biasv;
        }
    }
    __syncthreads();
    // phase 2: gate GEMM, wave wv -> cols wv*32..+32, M=8 (rows 8..15 garbage)
    int l = tid & 63;
    int lr = l & 15, lq = l >> 4;
    f32x4 acc[2];
    acc[0] = (f32x4)0.f; acc[1] = (f32x4)0.f;
    for (int ks = 0; ks < 8; ++ks) {
        bf16x8 ah, al, bh8[2], bl8[2];
        {
            int row = lr & 7;   // clamp: only 8 rows staged
            int baddr = (row * 512 + ks * 64 + lq * 16) ^ ((row & 7) << 4);
            ah = *(const bf16x8*)((const char*)Ahi + baddr);
            al = *(const bf16x8*)((const char*)Alo + baddr);
        }
        int kb = ks * 32 + lq * 8;
        #pragma unroll
        for (int ni = 0; ni < 2; ++ni) {
            int col = wv * 32 + ni * 16 + lr;
            const float4* hp = (const float4*)(Hw + (size_t)col * 256 + kb);
            float4 va = hp[0], vb = hp[1];
            float xv[8] = {va.x, va.y, va.z, va.w, vb.x, vb.y, vb.z, vb.w};
            split8(xv, bh8[ni], bl8[ni]);
        }
        #pragma unroll
        for (int ni = 0; ni < 2; ++ni) {
            acc[ni] = __builtin_amdgcn_mfma_f32_16x16x32_bf16(ah, bh8[ni], acc[ni], 0, 0, 0);
            acc[ni] = __builtin_amdgcn_mfma_f32_16x16x32_bf16(ah, bl8[ni], acc[ni], 0, 0, 0);
            acc[ni] = __builtin_amdgcn_mfma_f32_16x16x32_bf16(al, bh8[ni], acc[ni], 0, 0, 0);
        }
    }
    // epilogue: gate + elu + mix (rows 0..7 only)
    #pragma unroll
    for (int ni = 0; ni < 2; ++ni) {
        int c = wv * 32 + ni * 16 + lr;
        float hbv = Hb[c];
        #pragma unroll
        for (int r = 0; r < 4; ++r) {
            int rl = lq * 4 + r;
            if (rl < 8) {
                size_t rg = (size_t)b * 2048 + brow + rl;
                float x = acc[ni][r] + hbv;
                float g = 1.f / (1.f + __expf(-x));
                float fo = FOUT[rl * FSTR + c];
                float e = fo > 0.f ? fo : expm1f(fo);
                float fs = feat_src[rg * 256 + c];
                out[rg * 256 + c] = g * e + (1.f - g) * fs;
            }
        }
    }
}

extern "C" void kernel_launch(void* const* d_in, const int* in_sizes, int n_in,
                              void* d_out, int out_size, void* d_ws, size_t ws_size,
                              hipStream_t stream) {
    const float* feat_src = (const float*)d_in[0];
    const float* feat_dst = (const float*)d_in[1];
    const float* W        = (const float*)d_in[2];
    const float* bias     = (const float*)d_in[3];
    const float* w_src    = (const float*)d_in[4];
    const float* w_dst    = (const float*)d_in[5];
    const float* Hw       = (const float*)d_in[6];
    const float* Hb       = (const float*)d_in[7];
    float* out = (float*)d_out;
    float* ws  = (float*)d_ws;

    k1_mfma<<<512, 256, 0, stream>>>(feat_src, feat_dst, W, w_src, w_dst, ws);
    kmid<<<16, 1024, 0, stream>>>(ws);
    k34<<<1024, 512, 0, stream>>>(feat_src, Hw, Hb, bias, ws, out);
}